// Round 9
// baseline (2039.033 us; speedup 1.0000x reference)
//
#include <hip/hip_runtime.h>
#include <cstdint>
#include <cstddef>

typedef unsigned short u16;
typedef __attribute__((ext_vector_type(8))) short short8;
typedef __attribute__((ext_vector_type(4))) float f32x4;

#define DEV __device__ __forceinline__

DEV float bf2f(u16 u) {
    union { float f; uint32_t i; } c; c.i = ((uint32_t)u) << 16; return c.f;
}
DEV u16 f2bf(float f) {
    union { float f; uint32_t i; } c; c.f = f;
    uint32_t r = c.i + 0x7FFF + ((c.i >> 16) & 1);
    return (u16)(r >> 16);
}

DEV void gload16(const void* g, void* l) {
    __builtin_amdgcn_global_load_lds(
        (const __attribute__((address_space(1))) void*)g,
        (__attribute__((address_space(3))) void*)l, 16, 0, 0);
}

template<int N> DEV void waitv() {
    if constexpr (N == 0)      asm volatile("s_waitcnt vmcnt(0)" ::: "memory");
    else if constexpr (N == 3) asm volatile("s_waitcnt vmcnt(3)" ::: "memory");
    else if constexpr (N == 4) asm volatile("s_waitcnt vmcnt(4)" ::: "memory");
    else if constexpr (N == 6) asm volatile("s_waitcnt vmcnt(6)" ::: "memory");
    else if constexpr (N == 8) asm volatile("s_waitcnt vmcnt(8)" ::: "memory");
    else                       asm volatile("s_waitcnt vmcnt(0)" ::: "memory");
}

// ---------------------------------------------------------------------------
// GEMM: C[M,N] = A[M,K] * Bt[N,K]^T (+ epilogue).
// NBUF=4 deep pipeline, ONE barrier per K-step:
//   step k: stage(k+3 -> buf[(k+3)&3])   (that buf was read at step k-1;
//                                          drained by step k-1's end barrier)
//           ds_read frags from buf[k&3]  (compiler-scheduled partial lgkmcnt)
//           MFMA
//           lgkmcnt(0); vmcnt(counted: tile k+1 landed); s_barrier
// No mid-step drain => ds_read latency, staging and MFMA overlap freely.
// LDS layout keeps r8 swizzle (neutral but harmless): slot ch=rp*8+s holds
// (row=2rp|(d&1), kslot=d>>1), d=s^(rp&7); reads use same involution.
// EPI 0: bf16 = acc+bias; 1: f32 = acc+bias+resid; 2: bf16 = gelu(acc+bias);
// EPI 3: bf16 = acc*scale; 4: bf16 = acc; 5: bf16 = acc+bias routed to 3
//        stacked [M,1024] buffers by col>>10 (fused QKV).
// ---------------------------------------------------------------------------
template<int WM, int WN, int MR, int NR, int EPI>
__global__ __launch_bounds__(256)
void gemm_bt(const u16* __restrict__ A, const u16* __restrict__ B, void* __restrict__ C,
             const float* __restrict__ bias, const float* __restrict__ resid,
             int K, int lda, int ldb, int ldc,
             int nh, long a_zb, long a_zh, long b_zb, long b_zh, long c_zb, long c_zh,
             float scale)
{
    static_assert(WM * WN == 4, "4 waves");
    constexpr int BM = WM * MR * 16;
    constexpr int BN = WN * NR * 16;
    constexpr int BK = 32;
    constexpr int NBUF = 4;
    __shared__ __align__(16) u16 As[NBUF * BM * BK];
    __shared__ __align__(16) u16 Bs[NBUF * BN * BK];

    const int tid  = threadIdx.x;
    const int lane = tid & 63;
    const int wid  = tid >> 6;
    const int zz = blockIdx.z;
    const int b = zz / nh, h = zz % nh;
    A += (long)b * a_zb + (long)h * a_zh;
    B += (long)b * b_zb + (long)h * b_zh;
    const long coff = (long)b * c_zb + (long)h * c_zh;
    const int m0 = blockIdx.x * BM, n0 = blockIdx.y * BN;

    f32x4 acc[MR][NR] = {};
    constexpr int AI = (BM * 4) / 256;   // 16B chunks per tile / threads
    constexpr int BI = (BN * 4) / 256;
    constexpr int L  = AI + BI;          // vmem loads per stage per thread

    const int wr = wid / WN, wc = wid % WN;
    const int lr = lane & 15, lk = lane >> 4;

    // staging: LDS slot ch = rp*8+s <- global (row=2rp|(d&1), kslot=d>>1), d=s^(rp&7)
    auto stage = [&](int buf, int k0) {
#pragma unroll
        for (int i = 0; i < AI; ++i) {
            int ch = (i << 8) + tid;
            int rp = ch >> 3, s = ch & 7;
            int d  = s ^ (rp & 7);
            const u16* g = A + (long)(m0 + ((rp << 1) | (d & 1))) * lda + k0 + ((d >> 1) << 3);
            gload16(g, (char*)As + (size_t)buf * (BM * BK * 2) + ch * 16);
        }
#pragma unroll
        for (int i = 0; i < BI; ++i) {
            int ch = (i << 8) + tid;
            int rp = ch >> 3, s = ch & 7;
            int d  = s ^ (rp & 7);
            const u16* g = B + (long)(n0 + ((rp << 1) | (d & 1))) * ldb + k0 + ((d >> 1) << 3);
            gload16(g, (char*)Bs + (size_t)buf * (BN * BK * 2) + ch * 16);
        }
    };

    // swizzled LDS read offset (u16 units) for (row, lk): rp*64 + s*8
    auto lds_off = [&](int row) -> int {
        int rp = row >> 1;
        int s  = ((lk << 1) | (row & 1)) ^ (rp & 7);
        return rp * 64 + s * 8;
    };

    const int nt = K >> 5;   // K-steps (all K are multiples of 32)

    // prologue: stage up to 3 tiles, wait for tile 0 only
    if (nt > 0) stage(0, 0);
    if (nt > 1) stage(1, BK);
    if (nt > 2) stage(2, 2 * BK);
    if (nt > 2)      waitv<2 * L>();
    else if (nt > 1) waitv<L>();
    else             waitv<0>();
    __builtin_amdgcn_s_barrier();

    for (int k = 0; k < nt; ++k) {
        // refill the buffer freed at step k-1 with tile k+3 (3-deep in flight)
        if (k + 3 < nt) stage((k + 3) & 3, (k + 3) * BK);

        const int cur = k & 3;
        const u16* Ac = As + (size_t)cur * (BM * BK);
        const u16* Bc = Bs + (size_t)cur * (BN * BK);
        short8 af[MR], bf[NR];
#pragma unroll
        for (int m = 0; m < MR; ++m)
            af[m] = *(const short8*)(Ac + lds_off(wr * MR * 16 + m * 16 + lr));
#pragma unroll
        for (int n = 0; n < NR; ++n)
            bf[n] = *(const short8*)(Bc + lds_off(wc * NR * 16 + n * 16 + lr));

#pragma unroll
        for (int m = 0; m < MR; ++m)
#pragma unroll
            for (int n = 0; n < NR; ++n)
                acc[m][n] = __builtin_amdgcn_mfma_f32_16x16x32_bf16(af[m], bf[n], acc[m][n], 0, 0, 0);

        // end of step: own ds_reads drained, tile k+1 landed, then barrier
        if (k + 1 < nt) {
            asm volatile("s_waitcnt lgkmcnt(0)" ::: "memory");
            if (k + 4 <= nt)      waitv<2 * L>();  // tiles k+2,k+3 in flight
            else if (k + 3 == nt) waitv<L>();      // tile k+2 in flight
            else                  waitv<0>();      // nothing beyond k+1
            __builtin_amdgcn_s_barrier();
        }
    }

    // epilogue: D lane layout: col = lane&15, row = (lane>>4)*4 + j
#pragma unroll
    for (int m = 0; m < MR; ++m) {
        const int rowb = m0 + wr * MR * 16 + m * 16 + (lane >> 4) * 4;
#pragma unroll
        for (int n = 0; n < NR; ++n) {
            const int col = n0 + wc * NR * 16 + n * 16 + lr;
            float bv = 0.f;
            if (EPI == 0 || EPI == 1 || EPI == 2 || EPI == 5) bv = bias[col];
#pragma unroll
            for (int j = 0; j < 4; ++j) {
                const long idx = coff + (long)(rowb + j) * ldc + col;
                float v = acc[m][n][j];
                if (EPI == 0) {
                    ((u16*)C)[idx] = f2bf(v + bv);
                } else if (EPI == 1) {
                    ((float*)C)[idx] = v + bv + resid[(long)(rowb + j) * ldc + col];
                } else if (EPI == 2) {
                    float t = v + bv;
                    ((u16*)C)[idx] = f2bf(0.5f * t * (1.0f + erff(t * 0.70710678118654752f)));
                } else if (EPI == 3) {
                    ((u16*)C)[idx] = f2bf(v * scale);
                } else if (EPI == 5) {
                    const long qidx = (long)(col >> 10) * 4194304L
                                    + (long)(rowb + j) * 1024 + (col & 1023);
                    ((u16*)C)[qidx] = f2bf(v + bv);
                } else {
                    ((u16*)C)[idx] = f2bf(v);
                }
            }
        }
    }
}

// ---------------------------------------------------------------------------
// weight transpose + f32->bf16: src fp32 [K,N] tile -> dst bf16 [row_off+N, K]
// ---------------------------------------------------------------------------
__global__ __launch_bounds__(256)
void wconv_kernel(const float* __restrict__ src, u16* __restrict__ dst,
                  int K, int N, int row_off)
{
    __shared__ __align__(16) float t[64][65];
    const float* s = src + (long)(blockIdx.y * 64) * N + blockIdx.x * 64;
    const int tid = threadIdx.x;
#pragma unroll
    for (int i = 0; i < 4; ++i) {
        int ch = (i << 8) + tid;
        int r = ch >> 4, c4 = ch & 15;
        float4 v = *(const float4*)(s + (long)r * N + c4 * 4);
        t[r][c4 * 4 + 0] = v.x; t[r][c4 * 4 + 1] = v.y;
        t[r][c4 * 4 + 2] = v.z; t[r][c4 * 4 + 3] = v.w;
    }
    __syncthreads();
    u16* d = dst + (long)(row_off + blockIdx.x * 64) * K + blockIdx.y * 64;
#pragma unroll
    for (int i = 0; i < 4; ++i) {
        int ch = (i << 8) + tid;
        int c = ch >> 4, k4 = ch & 15;
        ushort4 o;
        o.x = f2bf(t[k4 * 4 + 0][c]);
        o.y = f2bf(t[k4 * 4 + 1][c]);
        o.z = f2bf(t[k4 * 4 + 2][c]);
        o.w = f2bf(t[k4 * 4 + 3][c]);
        *(ushort4*)(d + (long)c * K + k4 * 4) = o;
    }
}

__global__ __launch_bounds__(256)
void bconcat_kernel(const float* __restrict__ bq, const float* __restrict__ bk,
                    const float* __restrict__ bv, float* __restrict__ out)
{
    int i = blockIdx.x * 256 + threadIdx.x;   // 6*3072 total
    int l = i / 3072, n = i % 3072;
    float v = (n < 1024) ? bq[l * 1024 + n]
            : (n < 2048) ? bk[l * 1024 + n - 1024]
                         : bv[l * 1024 + n - 2048];
    out[i] = v;
}

// ---------------------------------------------------------------------------
// embedding: x = tok_emb[seq] + PE + seg_emb[seg]; writes f32 + bf16
// ---------------------------------------------------------------------------
__global__ __launch_bounds__(256)
void embed_kernel(const int* __restrict__ seq, const int* __restrict__ seg,
                  const float* __restrict__ tok, const float* __restrict__ sege,
                  float* __restrict__ x, u16* __restrict__ xb)
{
    long i = ((long)blockIdx.x << 8) + threadIdx.x;  // B*L*512 pairs
    int d2 = (int)(i & 511);
    long bl = i >> 9;
    int l = (int)(bl & 511);
    int t = seq[bl];
    int g = seg[bl];
    float div = powf(10000.f, -(float)(2 * d2) * (1.0f / 1024.f));
    float arg = (float)l * div;
    float sv = sinf(arg), cv = cosf(arg);
    long toff = (long)t * 1024 + 2 * d2;
    long goff = (long)g * 1024 + 2 * d2;
    float x0 = tok[toff]     + sv + sege[goff];
    float x1 = tok[toff + 1] + cv + sege[goff + 1];
    long xo = (bl << 10) + 2 * d2;
    x[xo] = x0; x[xo + 1] = x1;
    xb[xo] = f2bf(x0); xb[xo + 1] = f2bf(x1);
}

// ---------------------------------------------------------------------------
// per-head V transpose: Vb flat per (b,h) = [512,64] row-major contiguous
//   -> vt per (b,h) = [64,512]
// ---------------------------------------------------------------------------
__global__ __launch_bounds__(256)
void vtrans_kernel(const u16* __restrict__ Vb, u16* __restrict__ vt)
{
    __shared__ __align__(16) u16 t[64][72];
    const int bh = blockIdx.y;           // 0..127
    const int l0 = blockIdx.x << 6;      // 0,64,...,448
    const u16* src = Vb + ((long)bh << 15) + (long)l0 * 64;   // contiguous 64x64
    const int tid = threadIdx.x;
#pragma unroll
    for (int i = 0; i < 2; ++i) {
        int ch = (i << 8) + tid;         // 0..511, 8 elems each
        int r = ch >> 3, c8 = ch & 7;
        short8 v = *(const short8*)(src + (long)r * 64 + (c8 << 3));
#pragma unroll
        for (int j = 0; j < 8; ++j) t[r][(c8 << 3) + j] = (u16)v[j];
    }
    __syncthreads();
    u16* d = vt + ((long)bh << 15) + l0;
#pragma unroll
    for (int i = 0; i < 2; ++i) {
        int ch = (i << 8) + tid;
        int dd = ch >> 3, l8 = ch & 7;
        short8 o;
#pragma unroll
        for (int j = 0; j < 8; ++j) o[j] = (short)t[(l8 << 3) + j][dd];
        *(short8*)(d + (long)dd * 512 + (l8 << 3)) = o;
    }
}

// ---------------------------------------------------------------------------
// masked softmax over rows of S [B*H*L, 512], bf16 in-place. one wave per row
// ---------------------------------------------------------------------------
__global__ __launch_bounds__(256)
void softmax_kernel(u16* __restrict__ S, const int* __restrict__ seq)
{
    long row = ((long)blockIdx.x << 2) + (threadIdx.x >> 6);
    int lane = threadIdx.x & 63;
    int b = (int)(row >> 13);   // / (H*L = 8192)
    u16* p = S + (row << 9);
    short8 raw = *(short8*)(p + (lane << 3));
    const int* sq = seq + (b << 9) + (lane << 3);
    float v[8];
#pragma unroll
    for (int i = 0; i < 8; ++i)
        v[i] = (sq[i] == 0) ? -1e9f : bf2f((u16)raw[i]);
    float mx = v[0];
#pragma unroll
    for (int i = 1; i < 8; ++i) mx = fmaxf(mx, v[i]);
#pragma unroll
    for (int o = 32; o; o >>= 1) mx = fmaxf(mx, __shfl_xor(mx, o));
    float e[8], sum = 0.f;
#pragma unroll
    for (int i = 0; i < 8; ++i) { e[i] = expf(v[i] - mx); sum += e[i]; }
#pragma unroll
    for (int o = 32; o; o >>= 1) sum += __shfl_xor(sum, o);
    float r = 1.0f / sum;
    short8 o8;
#pragma unroll
    for (int i = 0; i < 8; ++i) o8[i] = (short)f2bf(e[i] * r);
    *(short8*)(p + (lane << 3)) = o8;
}

// ---------------------------------------------------------------------------
// LayerNorm over D=1024, block per row; writes f32 (residual stream) + bf16
// ---------------------------------------------------------------------------
__global__ __launch_bounds__(256)
void ln_kernel(const float* __restrict__ in, float* __restrict__ xout, u16* __restrict__ xbout)
{
    const int row = blockIdx.x;
    const int tid = threadIdx.x;
    const float4 v = ((const float4*)(in + (long)row * 1024))[tid];
    float s = v.x + v.y + v.z + v.w;
#pragma unroll
    for (int o = 32; o; o >>= 1) s += __shfl_down(s, o);
    __shared__ float red[8];
    const int wid = tid >> 6, lane = tid & 63;
    if (lane == 0) red[wid] = s;
    __syncthreads();
    const float mean = (red[0] + red[1] + red[2] + red[3]) * (1.0f / 1024.f);
    const float dx = v.x - mean, dy = v.y - mean, dz = v.z - mean, dw = v.w - mean;
    float q = dx * dx + dy * dy + dz * dz + dw * dw;
#pragma unroll
    for (int o = 32; o; o >>= 1) q += __shfl_down(q, o);
    if (lane == 0) red[4 + wid] = q;
    __syncthreads();
    const float var = (red[4] + red[5] + red[6] + red[7]) * (1.0f / 1024.f);
    const float inv = rsqrtf(var + 1e-5f);
    float4 o4;
    o4.x = dx * inv; o4.y = dy * inv; o4.z = dz * inv; o4.w = dw * inv;
    ((float4*)(xout + (long)row * 1024))[tid] = o4;
    ushort4 ob;
    ob.x = f2bf(o4.x); ob.y = f2bf(o4.y); ob.z = f2bf(o4.z); ob.w = f2bf(o4.w);
    ((ushort4*)(xbout + (long)row * 1024))[tid] = ob;
}

// ---------------------------------------------------------------------------
extern "C" void kernel_launch(void* const* d_in, const int* in_sizes, int n_in,
                              void* d_out, int out_size, void* d_ws, size_t ws_size,
                              hipStream_t stream)
{
    const int*   seqp = (const int*)d_in[0];
    const int*   segp = (const int*)d_in[1];
    const float* tok  = (const float*)d_in[2];
    const float* sege = (const float*)d_in[3];
    const float* Wq = (const float*)d_in[4];  const float* bq = (const float*)d_in[5];
    const float* Wk = (const float*)d_in[6];  const float* bk = (const float*)d_in[7];
    const float* Wv = (const float*)d_in[8];  const float* bv = (const float*)d_in[9];
    const float* Wo = (const float*)d_in[10]; const float* bo = (const float*)d_in[11];
    const float* W1 = (const float*)d_in[12]; const float* b1 = (const float*)d_in[13];
    const float* W2 = (const float*)d_in[14]; const float* b2 = (const float*)d_in[15];

    // ---- workspace (lifetime-aliased; ~160 MB) ----
    char* w = (char*)d_ws;
    auto take = [&](size_t bytes) -> void* {
        void* p = (void*)w; w += (bytes + 255) & ~(size_t)255; return p;
    };
    float* x    = (float*)take(4096UL * 1024 * 4);     // 16 MB residual f32
    u16*   xb   = (u16*)  take(4096UL * 1024 * 2);     //  8 MB residual bf16
    float* tmp  = (float*)take(4096UL * 1024 * 4);     // 16 MB pre-LN f32
    u16*   R1   = (u16*)  take(128UL * 512 * 512 * 2); // 64 MB: S then hbuf
    u16*   qkv3 = (u16*)  take(3UL * 4096 * 1024 * 2); // 24 MB Q|K|V stacked
    u16*   ctx  = (u16*)  take(4096UL * 1024 * 2);     //  8 MB
    u16*   vt   = (u16*)  take(128UL * 64 * 512 * 2);  //  8 MB
    u16*   qkvw = (u16*)  take(3072UL * 1024 * 2);     //  6 MB W_{q,k,v}^T
    u16*   wo_t = (u16*)  take(1024UL * 1024 * 2);     //  2 MB
    u16*   w1_t = (u16*)  take(4096UL * 1024 * 2);     //  8 MB
    u16*   w2_t = (u16*)  take(1024UL * 4096 * 2);     //  8 MB
    float* bqkv = (float*)take(6UL * 3072 * 4);

    u16* S    = R1;              // scores [B,H,512,512] bf16
    u16* hbuf = R1;              // FFN hidden [4096,4096] (S dead by then)
    u16* Qb   = qkv3;            // [4096,1024] each; heads = contiguous chunks
    u16* Kb   = qkv3 + 4194304L;
    u16* Vb   = qkv3 + 8388608L;

    bconcat_kernel<<<72, 256, 0, stream>>>(bq, bk, bv, bqkv);
    embed_kernel<<<8192, 256, 0, stream>>>(seqp, segp, tok, sege, x, xb);

    for (int l = 0; l < 6; ++l) {
        // per-layer weight conversion (transpose + bf16)
        wconv_kernel<<<dim3(16, 16), 256, 0, stream>>>(Wq + (long)l * 1048576L, qkvw, 1024, 1024, 0);
        wconv_kernel<<<dim3(16, 16), 256, 0, stream>>>(Wk + (long)l * 1048576L, qkvw, 1024, 1024, 1024);
        wconv_kernel<<<dim3(16, 16), 256, 0, stream>>>(Wv + (long)l * 1048576L, qkvw, 1024, 1024, 2048);
        wconv_kernel<<<dim3(16, 16), 256, 0, stream>>>(Wo + (long)l * 1048576L, wo_t, 1024, 1024, 0);
        wconv_kernel<<<dim3(64, 16), 256, 0, stream>>>(W1 + (long)l * 4194304L, w1_t, 1024, 4096, 0);
        wconv_kernel<<<dim3(16, 64), 256, 0, stream>>>(W2 + (long)l * 4194304L, w2_t, 4096, 1024, 0);

        // fused QKV projection: [4096,1024] x [3072,1024]^T (64x128 tiles,
        // 1536 blocks); epilogue routes col>>10 to Qb/Kb/Vb
        gemm_bt<1, 4, 4, 2, 5><<<dim3(64, 24, 1), 256, 0, stream>>>(
            xb, qkvw, qkv3, bqkv + l * 3072, nullptr,
            1024, 1024, 1024, 1024, 1, 0, 0, 0, 0, 0, 0, 1.f);

        // per-head V transpose: [512,64] -> [64,512]
        vtrans_kernel<<<dim3(8, 128), 256, 0, stream>>>(Vb, vt);

        // scores per (b,h): Q2[512,64] @ K2[512,64]^T * 0.125
        gemm_bt<2, 2, 4, 4, 3><<<dim3(4, 4, 128), 256, 0, stream>>>(
            Qb, Kb, S, nullptr, nullptr,
            64, 64, 64, 512,
            16, 524288L, 32768L, 524288L, 32768L, 4194304L, 262144L, 0.125f);

        // masked softmax (in place)
        softmax_kernel<<<16384, 256, 0, stream>>>(S, seqp);

        // context per (b,h): P[512,512] @ Vt[64,512]^T -> ctx chunk [512,64]
        gemm_bt<4, 1, 2, 4, 4><<<dim3(4, 1, 128), 256, 0, stream>>>(
            S, vt, ctx, nullptr, nullptr,
            512, 512, 512, 64,
            16, 4194304L, 262144L, 524288L, 32768L, 524288L, 32768L, 1.f);

        // output projection + bias + residual -> tmp fp32 (64x128, 512 blocks)
        gemm_bt<1, 4, 4, 2, 1><<<dim3(64, 8, 1), 256, 0, stream>>>(
            ctx, wo_t, tmp, bo + l * 1024, x,
            1024, 1024, 1024, 1024, 1, 0, 0, 0, 0, 0, 0, 1.f);

        // LN -> x (f32 residual) + xb (bf16)
        ln_kernel<<<4096, 256, 0, stream>>>(tmp, x, xb);

        // FFN1 + exact GELU -> hbuf bf16 [4096,4096] (64x128, 2048 blocks)
        gemm_bt<1, 4, 4, 2, 2><<<dim3(64, 32, 1), 256, 0, stream>>>(
            xb, w1_t, hbuf, b1 + l * 4096, nullptr,
            1024, 1024, 1024, 4096, 1, 0, 0, 0, 0, 0, 0, 1.f);

        // FFN2 + bias + residual -> tmp fp32 (64x128, 512 blocks)
        gemm_bt<1, 4, 4, 2, 1><<<dim3(64, 8, 1), 256, 0, stream>>>(
            hbuf, w2_t, tmp, b2 + l * 1024, x,
            4096, 4096, 4096, 1024, 1, 0, 0, 0, 0, 0, 0, 1.f);

        // LN -> x / d_out
        ln_kernel<<<4096, 256, 0, stream>>>(tmp, (l == 5) ? (float*)d_out : x, xb);
    }
}

// Round 10
// 1818.807 us; speedup vs baseline: 1.1211x; 1.1211x over previous
//
#include <hip/hip_runtime.h>
#include <cstdint>
#include <cstddef>

typedef unsigned short u16;
typedef __attribute__((ext_vector_type(8))) short short8;
typedef __attribute__((ext_vector_type(4))) float f32x4;

#define DEV __device__ __forceinline__

DEV float bf2f(u16 u) {
    union { float f; uint32_t i; } c; c.i = ((uint32_t)u) << 16; return c.f;
}
DEV u16 f2bf(float f) {
    union { float f; uint32_t i; } c; c.f = f;
    uint32_t r = c.i + 0x7FFF + ((c.i >> 16) & 1);
    return (u16)(r >> 16);
}

DEV void gload16(const void* g, void* l) {
    __builtin_amdgcn_global_load_lds(
        (const __attribute__((address_space(1))) void*)g,
        (__attribute__((address_space(3))) void*)l, 16, 0, 0);
}

template<int N> DEV void waitv() {
    if constexpr (N == 0)      asm volatile("s_waitcnt vmcnt(0)" ::: "memory");
    else if constexpr (N == 2) asm volatile("s_waitcnt vmcnt(2)" ::: "memory");
    else if constexpr (N == 3) asm volatile("s_waitcnt vmcnt(3)" ::: "memory");
    else if constexpr (N == 4) asm volatile("s_waitcnt vmcnt(4)" ::: "memory");
    else if constexpr (N == 6) asm volatile("s_waitcnt vmcnt(6)" ::: "memory");
    else if constexpr (N == 8) asm volatile("s_waitcnt vmcnt(8)" ::: "memory");
    else                       asm volatile("s_waitcnt vmcnt(0)" ::: "memory");
}

// ---------------------------------------------------------------------------
// GEMM: C[M,N] = A[M,K] * Bt[N,K]^T (+ epilogue).
// r7-proven loop: NBUF=3, counted vmcnt, per-step {reads; lgkmcnt0; BAR;
// stage(k+3); MFMA; vmcnt(counted); BAR}. This round's single change: the
// big-GEMM instantiations run 8 waves / 512 threads (2Mx4N, 64x32 per wave)
// so each SIMD holds >=2 waves whose stalls interleave (grid of 256 blocks
// pigeonholes to 1 block/CU; 4-wave blocks left each SIMD with ONE wave).
// LDS r8 swizzle (neutral, kept): slot ch=rp*8+s holds (row=2rp|(d&1),
// kslot=d>>1), d=s^(rp&7); reads use the same involution.
// EPI 0: bf16 = acc+bias; 1: f32 = acc+bias+resid; 2: bf16 = gelu(acc+bias);
// EPI 3: bf16 = acc*scale; 4: bf16 = acc; 5: bf16 = acc+bias routed to 3
//        stacked [M,1024] buffers by col>>10 (fused QKV).
// ---------------------------------------------------------------------------
template<int WM, int WN, int MR, int NR, int EPI>
__global__ __launch_bounds__(WM * WN * 64)
void gemm_bt(const u16* __restrict__ A, const u16* __restrict__ B, void* __restrict__ C,
             const float* __restrict__ bias, const float* __restrict__ resid,
             int K, int lda, int ldb, int ldc,
             int nh, long a_zb, long a_zh, long b_zb, long b_zh, long c_zb, long c_zh,
             float scale)
{
    static_assert(WM * WN == 4 || WM * WN == 8, "4 or 8 waves");
    constexpr int THREADS = WM * WN * 64;
    constexpr int BM = WM * MR * 16;
    constexpr int BN = WN * NR * 16;
    constexpr int BK = 32;
    constexpr int NBUF = 3;
    __shared__ __align__(16) u16 As[NBUF * BM * BK];
    __shared__ __align__(16) u16 Bs[NBUF * BN * BK];

    const int tid  = threadIdx.x;
    const int lane = tid & 63;
    const int wid  = tid >> 6;
    const int zz = blockIdx.z;
    const int b = zz / nh, h = zz % nh;
    A += (long)b * a_zb + (long)h * a_zh;
    B += (long)b * b_zb + (long)h * b_zh;
    const long coff = (long)b * c_zb + (long)h * c_zh;
    const int m0 = blockIdx.x * BM, n0 = blockIdx.y * BN;

    f32x4 acc[MR][NR] = {};
    constexpr int AI = (BM * 4) / THREADS;   // 16B chunks per tile / threads
    constexpr int BI = (BN * 4) / THREADS;
    constexpr int L  = AI + BI;              // vmem loads per stage per thread

    const int wr = wid / WN, wc = wid % WN;
    const int lr = lane & 15, lk = lane >> 4;

    // staging: LDS slot ch = rp*8+s <- global (row=2rp|(d&1), kslot=d>>1), d=s^(rp&7)
    auto stage = [&](int buf, int k0) {
#pragma unroll
        for (int i = 0; i < AI; ++i) {
            int ch = i * THREADS + tid;
            int rp = ch >> 3, s = ch & 7;
            int d  = s ^ (rp & 7);
            const u16* g = A + (long)(m0 + ((rp << 1) | (d & 1))) * lda + k0 + ((d >> 1) << 3);
            gload16(g, (char*)As + (size_t)buf * (BM * BK * 2) + ch * 16);
        }
#pragma unroll
        for (int i = 0; i < BI; ++i) {
            int ch = i * THREADS + tid;
            int rp = ch >> 3, s = ch & 7;
            int d  = s ^ (rp & 7);
            const u16* g = B + (long)(n0 + ((rp << 1) | (d & 1))) * ldb + k0 + ((d >> 1) << 3);
            gload16(g, (char*)Bs + (size_t)buf * (BN * BK * 2) + ch * 16);
        }
    };

    // swizzled LDS read offset (u16 units) for (row, lk): rp*64 + s*8
    auto lds_off = [&](int row) -> int {
        int rp = row >> 1;
        int s  = ((lk << 1) | (row & 1)) ^ (rp & 7);
        return rp * 64 + s * 8;
    };

    const int nt = K >> 5;   // K-steps (all K are multiples of 32)

    // prologue: stage up to 3 tiles, then wait for tile 0 only
    if (nt > 0) stage(0, 0);
    if (nt > 1) stage(1, BK);
    if (nt > 2) stage(2, 2 * BK);
    if (nt > 2)      waitv<2 * L>();
    else if (nt > 1) waitv<L>();
    else             waitv<0>();
    __builtin_amdgcn_s_barrier();

    for (int k = 0; k < nt; ++k) {
        const int cur = k % 3;
        const u16* Ac = As + (size_t)cur * (BM * BK);
        const u16* Bc = Bs + (size_t)cur * (BN * BK);
        short8 af[MR], bf[NR];
#pragma unroll
        for (int m = 0; m < MR; ++m)
            af[m] = *(const short8*)(Ac + lds_off(wr * MR * 16 + m * 16 + lr));
#pragma unroll
        for (int n = 0; n < NR; ++n)
            bf[n] = *(const short8*)(Bc + lds_off(wc * NR * 16 + n * 16 + lr));

        // our reads of buf[cur] are complete; sync so no wave still reads it
        asm volatile("s_waitcnt lgkmcnt(0)" ::: "memory");
        __builtin_amdgcn_s_barrier();

        // refill buf[cur] with tile k+3 (stays in flight across next 2 steps)
        if (k + 3 < nt) stage(cur, (k + 3) * BK);

#pragma unroll
        for (int m = 0; m < MR; ++m)
#pragma unroll
            for (int n = 0; n < NR; ++n)
                acc[m][n] = __builtin_amdgcn_mfma_f32_16x16x32_bf16(af[m], bf[n], acc[m][n], 0, 0, 0);

        // ensure tile k+1 landed (own loads via vmcnt, all waves via barrier)
        if (k + 1 < nt) {
            if (k + 4 <= nt)      waitv<2 * L>();  // tiles k+2,k+3 in flight
            else if (k + 3 == nt) waitv<L>();      // tile k+2 in flight
            else                  waitv<0>();      // nothing beyond k+1
            __builtin_amdgcn_s_barrier();
        }
    }

    // epilogue: D lane layout: col = lane&15, row = (lane>>4)*4 + j
#pragma unroll
    for (int m = 0; m < MR; ++m) {
        const int rowb = m0 + wr * MR * 16 + m * 16 + (lane >> 4) * 4;
#pragma unroll
        for (int n = 0; n < NR; ++n) {
            const int col = n0 + wc * NR * 16 + n * 16 + lr;
            float bv = 0.f;
            if (EPI == 0 || EPI == 1 || EPI == 2 || EPI == 5) bv = bias[col];
#pragma unroll
            for (int j = 0; j < 4; ++j) {
                const long idx = coff + (long)(rowb + j) * ldc + col;
                float v = acc[m][n][j];
                if (EPI == 0) {
                    ((u16*)C)[idx] = f2bf(v + bv);
                } else if (EPI == 1) {
                    ((float*)C)[idx] = v + bv + resid[(long)(rowb + j) * ldc + col];
                } else if (EPI == 2) {
                    float t = v + bv;
                    ((u16*)C)[idx] = f2bf(0.5f * t * (1.0f + erff(t * 0.70710678118654752f)));
                } else if (EPI == 3) {
                    ((u16*)C)[idx] = f2bf(v * scale);
                } else if (EPI == 5) {
                    const long qidx = (long)(col >> 10) * 4194304L
                                    + (long)(rowb + j) * 1024 + (col & 1023);
                    ((u16*)C)[qidx] = f2bf(v + bv);
                } else {
                    ((u16*)C)[idx] = f2bf(v);
                }
            }
        }
    }
}

// ---------------------------------------------------------------------------
// weight transpose + f32->bf16: src fp32 [K,N] tile -> dst bf16 [row_off+N, K]
// ---------------------------------------------------------------------------
__global__ __launch_bounds__(256)
void wconv_kernel(const float* __restrict__ src, u16* __restrict__ dst,
                  int K, int N, int row_off)
{
    __shared__ __align__(16) float t[64][65];
    const float* s = src + (long)(blockIdx.y * 64) * N + blockIdx.x * 64;
    const int tid = threadIdx.x;
#pragma unroll
    for (int i = 0; i < 4; ++i) {
        int ch = (i << 8) + tid;
        int r = ch >> 4, c4 = ch & 15;
        float4 v = *(const float4*)(s + (long)r * N + c4 * 4);
        t[r][c4 * 4 + 0] = v.x; t[r][c4 * 4 + 1] = v.y;
        t[r][c4 * 4 + 2] = v.z; t[r][c4 * 4 + 3] = v.w;
    }
    __syncthreads();
    u16* d = dst + (long)(row_off + blockIdx.x * 64) * K + blockIdx.y * 64;
#pragma unroll
    for (int i = 0; i < 4; ++i) {
        int ch = (i << 8) + tid;
        int c = ch >> 4, k4 = ch & 15;
        ushort4 o;
        o.x = f2bf(t[k4 * 4 + 0][c]);
        o.y = f2bf(t[k4 * 4 + 1][c]);
        o.z = f2bf(t[k4 * 4 + 2][c]);
        o.w = f2bf(t[k4 * 4 + 3][c]);
        *(ushort4*)(d + (long)c * K + k4 * 4) = o;
    }
}

__global__ __launch_bounds__(256)
void bconcat_kernel(const float* __restrict__ bq, const float* __restrict__ bk,
                    const float* __restrict__ bv, float* __restrict__ out)
{
    int i = blockIdx.x * 256 + threadIdx.x;   // 6*3072 total
    int l = i / 3072, n = i % 3072;
    float v = (n < 1024) ? bq[l * 1024 + n]
            : (n < 2048) ? bk[l * 1024 + n - 1024]
                         : bv[l * 1024 + n - 2048];
    out[i] = v;
}

// ---------------------------------------------------------------------------
// embedding: x = tok_emb[seq] + PE + seg_emb[seg]; writes f32 + bf16
// ---------------------------------------------------------------------------
__global__ __launch_bounds__(256)
void embed_kernel(const int* __restrict__ seq, const int* __restrict__ seg,
                  const float* __restrict__ tok, const float* __restrict__ sege,
                  float* __restrict__ x, u16* __restrict__ xb)
{
    long i = ((long)blockIdx.x << 8) + threadIdx.x;  // B*L*512 pairs
    int d2 = (int)(i & 511);
    long bl = i >> 9;
    int l = (int)(bl & 511);
    int t = seq[bl];
    int g = seg[bl];
    float div = powf(10000.f, -(float)(2 * d2) * (1.0f / 1024.f));
    float arg = (float)l * div;
    float sv = sinf(arg), cv = cosf(arg);
    long toff = (long)t * 1024 + 2 * d2;
    long goff = (long)g * 1024 + 2 * d2;
    float x0 = tok[toff]     + sv + sege[goff];
    float x1 = tok[toff + 1] + cv + sege[goff + 1];
    long xo = (bl << 10) + 2 * d2;
    x[xo] = x0; x[xo + 1] = x1;
    xb[xo] = f2bf(x0); xb[xo + 1] = f2bf(x1);
}

// ---------------------------------------------------------------------------
// per-head V transpose: Vb flat per (b,h) = [512,64] row-major contiguous
//   -> vt per (b,h) = [64,512]
// ---------------------------------------------------------------------------
__global__ __launch_bounds__(256)
void vtrans_kernel(const u16* __restrict__ Vb, u16* __restrict__ vt)
{
    __shared__ __align__(16) u16 t[64][72];
    const int bh = blockIdx.y;           // 0..127
    const int l0 = blockIdx.x << 6;      // 0,64,...,448
    const u16* src = Vb + ((long)bh << 15) + (long)l0 * 64;   // contiguous 64x64
    const int tid = threadIdx.x;
#pragma unroll
    for (int i = 0; i < 2; ++i) {
        int ch = (i << 8) + tid;         // 0..511, 8 elems each
        int r = ch >> 3, c8 = ch & 7;
        short8 v = *(const short8*)(src + (long)r * 64 + (c8 << 3));
#pragma unroll
        for (int j = 0; j < 8; ++j) t[r][(c8 << 3) + j] = (u16)v[j];
    }
    __syncthreads();
    u16* d = vt + ((long)bh << 15) + l0;
#pragma unroll
    for (int i = 0; i < 2; ++i) {
        int ch = (i << 8) + tid;
        int dd = ch >> 3, l8 = ch & 7;
        short8 o;
#pragma unroll
        for (int j = 0; j < 8; ++j) o[j] = (short)t[(l8 << 3) + j][dd];
        *(short8*)(d + (long)dd * 512 + (l8 << 3)) = o;
    }
}

// ---------------------------------------------------------------------------
// masked softmax over rows of S [B*H*L, 512], bf16 in-place. one wave per row
// ---------------------------------------------------------------------------
__global__ __launch_bounds__(256)
void softmax_kernel(u16* __restrict__ S, const int* __restrict__ seq)
{
    long row = ((long)blockIdx.x << 2) + (threadIdx.x >> 6);
    int lane = threadIdx.x & 63;
    int b = (int)(row >> 13);   // / (H*L = 8192)
    u16* p = S + (row << 9);
    short8 raw = *(short8*)(p + (lane << 3));
    const int* sq = seq + (b << 9) + (lane << 3);
    float v[8];
#pragma unroll
    for (int i = 0; i < 8; ++i)
        v[i] = (sq[i] == 0) ? -1e9f : bf2f((u16)raw[i]);
    float mx = v[0];
#pragma unroll
    for (int i = 1; i < 8; ++i) mx = fmaxf(mx, v[i]);
#pragma unroll
    for (int o = 32; o; o >>= 1) mx = fmaxf(mx, __shfl_xor(mx, o));
    float e[8], sum = 0.f;
#pragma unroll
    for (int i = 0; i < 8; ++i) { e[i] = expf(v[i] - mx); sum += e[i]; }
#pragma unroll
    for (int o = 32; o; o >>= 1) sum += __shfl_xor(sum, o);
    float r = 1.0f / sum;
    short8 o8;
#pragma unroll
    for (int i = 0; i < 8; ++i) o8[i] = (short)f2bf(e[i] * r);
    *(short8*)(p + (lane << 3)) = o8;
}

// ---------------------------------------------------------------------------
// LayerNorm over D=1024, block per row; writes f32 (residual stream) + bf16
// ---------------------------------------------------------------------------
__global__ __launch_bounds__(256)
void ln_kernel(const float* __restrict__ in, float* __restrict__ xout, u16* __restrict__ xbout)
{
    const int row = blockIdx.x;
    const int tid = threadIdx.x;
    const float4 v = ((const float4*)(in + (long)row * 1024))[tid];
    float s = v.x + v.y + v.z + v.w;
#pragma unroll
    for (int o = 32; o; o >>= 1) s += __shfl_down(s, o);
    __shared__ float red[8];
    const int wid = tid >> 6, lane = tid & 63;
    if (lane == 0) red[wid] = s;
    __syncthreads();
    const float mean = (red[0] + red[1] + red[2] + red[3]) * (1.0f / 1024.f);
    const float dx = v.x - mean, dy = v.y - mean, dz = v.z - mean, dw = v.w - mean;
    float q = dx * dx + dy * dy + dz * dz + dw * dw;
#pragma unroll
    for (int o = 32; o; o >>= 1) q += __shfl_down(q, o);
    if (lane == 0) red[4 + wid] = q;
    __syncthreads();
    const float var = (red[4] + red[5] + red[6] + red[7]) * (1.0f / 1024.f);
    const float inv = rsqrtf(var + 1e-5f);
    float4 o4;
    o4.x = dx * inv; o4.y = dy * inv; o4.z = dz * inv; o4.w = dw * inv;
    ((float4*)(xout + (long)row * 1024))[tid] = o4;
    ushort4 ob;
    ob.x = f2bf(o4.x); ob.y = f2bf(o4.y); ob.z = f2bf(o4.z); ob.w = f2bf(o4.w);
    ((ushort4*)(xbout + (long)row * 1024))[tid] = ob;
}

// ---------------------------------------------------------------------------
extern "C" void kernel_launch(void* const* d_in, const int* in_sizes, int n_in,
                              void* d_out, int out_size, void* d_ws, size_t ws_size,
                              hipStream_t stream)
{
    const int*   seqp = (const int*)d_in[0];
    const int*   segp = (const int*)d_in[1];
    const float* tok  = (const float*)d_in[2];
    const float* sege = (const float*)d_in[3];
    const float* Wq = (const float*)d_in[4];  const float* bq = (const float*)d_in[5];
    const float* Wk = (const float*)d_in[6];  const float* bk = (const float*)d_in[7];
    const float* Wv = (const float*)d_in[8];  const float* bv = (const float*)d_in[9];
    const float* Wo = (const float*)d_in[10]; const float* bo = (const float*)d_in[11];
    const float* W1 = (const float*)d_in[12]; const float* b1 = (const float*)d_in[13];
    const float* W2 = (const float*)d_in[14]; const float* b2 = (const float*)d_in[15];

    // ---- workspace (lifetime-aliased; ~160 MB) ----
    char* w = (char*)d_ws;
    auto take = [&](size_t bytes) -> void* {
        void* p = (void*)w; w += (bytes + 255) & ~(size_t)255; return p;
    };
    float* x    = (float*)take(4096UL * 1024 * 4);     // 16 MB residual f32
    u16*   xb   = (u16*)  take(4096UL * 1024 * 2);     //  8 MB residual bf16
    float* tmp  = (float*)take(4096UL * 1024 * 4);     // 16 MB pre-LN f32
    u16*   R1   = (u16*)  take(128UL * 512 * 512 * 2); // 64 MB: S then hbuf
    u16*   qkv3 = (u16*)  take(3UL * 4096 * 1024 * 2); // 24 MB Q|K|V stacked
    u16*   ctx  = (u16*)  take(4096UL * 1024 * 2);     //  8 MB
    u16*   vt   = (u16*)  take(128UL * 64 * 512 * 2);  //  8 MB
    u16*   qkvw = (u16*)  take(3072UL * 1024 * 2);     //  6 MB W_{q,k,v}^T
    u16*   wo_t = (u16*)  take(1024UL * 1024 * 2);     //  2 MB
    u16*   w1_t = (u16*)  take(4096UL * 1024 * 2);     //  8 MB
    u16*   w2_t = (u16*)  take(1024UL * 4096 * 2);     //  8 MB
    float* bqkv = (float*)take(6UL * 3072 * 4);

    u16* S    = R1;              // scores [B,H,512,512] bf16
    u16* hbuf = R1;              // FFN hidden [4096,4096] (S dead by then)
    u16* Qb   = qkv3;            // [4096,1024] each; heads = contiguous chunks
    u16* Kb   = qkv3 + 4194304L;
    u16* Vb   = qkv3 + 8388608L;

    bconcat_kernel<<<72, 256, 0, stream>>>(bq, bk, bv, bqkv);
    embed_kernel<<<8192, 256, 0, stream>>>(seqp, segp, tok, sege, x, xb);

    for (int l = 0; l < 6; ++l) {
        // per-layer weight conversion (transpose + bf16)
        wconv_kernel<<<dim3(16, 16), 256, 0, stream>>>(Wq + (long)l * 1048576L, qkvw, 1024, 1024, 0);
        wconv_kernel<<<dim3(16, 16), 256, 0, stream>>>(Wk + (long)l * 1048576L, qkvw, 1024, 1024, 1024);
        wconv_kernel<<<dim3(16, 16), 256, 0, stream>>>(Wv + (long)l * 1048576L, qkvw, 1024, 1024, 2048);
        wconv_kernel<<<dim3(16, 16), 256, 0, stream>>>(Wo + (long)l * 1048576L, wo_t, 1024, 1024, 0);
        wconv_kernel<<<dim3(64, 16), 256, 0, stream>>>(W1 + (long)l * 4194304L, w1_t, 1024, 4096, 0);
        wconv_kernel<<<dim3(16, 64), 256, 0, stream>>>(W2 + (long)l * 4194304L, w2_t, 4096, 1024, 0);

        // fused QKV projection: [4096,1024] x [3072,1024]^T, 128^2 tiles,
        // 8-wave blocks; epilogue routes col>>10 to Qb/Kb/Vb
        gemm_bt<2, 4, 4, 2, 5><<<dim3(32, 24, 1), 512, 0, stream>>>(
            xb, qkvw, qkv3, bqkv + l * 3072, nullptr,
            1024, 1024, 1024, 1024, 1, 0, 0, 0, 0, 0, 0, 1.f);

        // per-head V transpose: [512,64] -> [64,512]
        vtrans_kernel<<<dim3(8, 128), 256, 0, stream>>>(Vb, vt);

        // scores per (b,h): Q2[512,64] @ K2[512,64]^T * 0.125  (4-wave)
        gemm_bt<2, 2, 4, 4, 3><<<dim3(4, 4, 128), 256, 0, stream>>>(
            Qb, Kb, S, nullptr, nullptr,
            64, 64, 64, 512,
            16, 524288L, 32768L, 524288L, 32768L, 4194304L, 262144L, 0.125f);

        // masked softmax (in place)
        softmax_kernel<<<16384, 256, 0, stream>>>(S, seqp);

        // context per (b,h): P[512,512] @ Vt[64,512]^T -> ctx chunk [512,64]
        gemm_bt<4, 1, 2, 4, 4><<<dim3(4, 1, 128), 256, 0, stream>>>(
            S, vt, ctx, nullptr, nullptr,
            512, 512, 512, 64,
            16, 4194304L, 262144L, 524288L, 32768L, 524288L, 32768L, 1.f);

        // output projection + bias + residual -> tmp fp32 (8-wave)
        gemm_bt<2, 4, 4, 2, 1><<<dim3(32, 8, 1), 512, 0, stream>>>(
            ctx, wo_t, tmp, bo + l * 1024, x,
            1024, 1024, 1024, 1024, 1, 0, 0, 0, 0, 0, 0, 1.f);

        // LN -> x (f32 residual) + xb (bf16)
        ln_kernel<<<4096, 256, 0, stream>>>(tmp, x, xb);

        // FFN1 + exact GELU -> hbuf bf16 [4096,4096] (8-wave)
        gemm_bt<2, 4, 4, 2, 2><<<dim3(32, 32, 1), 512, 0, stream>>>(
            xb, w1_t, hbuf, b1 + l * 4096, nullptr,
            1024, 1024, 1024, 4096, 1, 0, 0, 0, 0, 0, 0, 1.f);

        // FFN2 + bias + residual -> tmp fp32 (8-wave)
        gemm_bt<2, 4, 4, 2, 1><<<dim3(32, 8, 1), 512, 0, stream>>>(
            hbuf, w2_t, tmp, b2 + l * 1024, x,
            4096, 4096, 4096, 1024, 1, 0, 0, 0, 0, 0, 0, 1.f);

        // LN -> x / d_out
        ln_kernel<<<4096, 256, 0, stream>>>(tmp, (l == 5) ? (float*)d_out : x, xb);
    }
}

// Round 11
// 1779.050 us; speedup vs baseline: 1.1461x; 1.0223x over previous
//
#include <hip/hip_runtime.h>
#include <cstdint>
#include <cstddef>

typedef unsigned short u16;
typedef __attribute__((ext_vector_type(8))) short short8;
typedef __attribute__((ext_vector_type(4))) float f32x4;

#define DEV __device__ __forceinline__

DEV float bf2f(u16 u) {
    union { float f; uint32_t i; } c; c.i = ((uint32_t)u) << 16; return c.f;
}
DEV u16 f2bf(float f) {
    union { float f; uint32_t i; } c; c.f = f;
    uint32_t r = c.i + 0x7FFF + ((c.i >> 16) & 1);
    return (u16)(r >> 16);
}

DEV void gload16(const void* g, void* l) {
    __builtin_amdgcn_global_load_lds(
        (const __attribute__((address_space(1))) void*)g,
        (__attribute__((address_space(3))) void*)l, 16, 0, 0);
}

template<int N> DEV void waitv() {
    if constexpr (N == 0)      asm volatile("s_waitcnt vmcnt(0)" ::: "memory");
    else if constexpr (N == 2) asm volatile("s_waitcnt vmcnt(2)" ::: "memory");
    else if constexpr (N == 3) asm volatile("s_waitcnt vmcnt(3)" ::: "memory");
    else if constexpr (N == 4) asm volatile("s_waitcnt vmcnt(4)" ::: "memory");
    else if constexpr (N == 6) asm volatile("s_waitcnt vmcnt(6)" ::: "memory");
    else if constexpr (N == 8) asm volatile("s_waitcnt vmcnt(8)" ::: "memory");
    else                       asm volatile("s_waitcnt vmcnt(0)" ::: "memory");
}

// ---------------------------------------------------------------------------
// gemm256: 256x256 tile, BK=32, 8 waves (2Mx4N, 128x64 per wave), NBUF=3,
// single end-of-step barrier + counted vmcnt, TWO MFMA sub-phases per step
// with B-frag register reuse (12 ds_read_b128/wave/step for 32 MFMA/wave).
// Step k: {read B0-3,A0-3 | stageA(k+2) | lgkm0 | prio1 16xMFMA prio0 |
//          read A4-7      | stageB(k+2) | lgkm0 | prio1 16xMFMA prio0 |
//          vmcnt(4: tile k+2 in flight, k+1 landed) | s_barrier}
// Race argument: stage at step k targets buf[(k+2)%3], last READ at step k-1,
// separated by step k-1's end barrier. Reads at step k need tile k landed:
// guaranteed by step k-1's vmcnt(4)+barrier. Accumulation order per output
// element identical to gemm_bt (k ascending) -> bit-identical results.
// EPI 2: bf16 = gelu(acc+bias); EPI 5: bf16 = acc+bias routed by col>>10.
// ---------------------------------------------------------------------------
template<int EPI>
__global__ __launch_bounds__(512)
void gemm256(const u16* __restrict__ A, const u16* __restrict__ B, void* __restrict__ C,
             const float* __restrict__ bias,
             int K, int lda, int ldb, int ldc)
{
    constexpr int THREADS = 512;
    constexpr int BM = 256, BN = 256, BK = 32;
    constexpr int MR = 8, NR = 4;
    __shared__ __align__(16) u16 As[3 * BM * BK];
    __shared__ __align__(16) u16 Bs[3 * BN * BK];

    const int tid = threadIdx.x, lane = tid & 63, wid = tid >> 6;
    const int wr = wid >> 2, wc = wid & 3;      // 2M x 4N waves
    const int lr = lane & 15, lk = lane >> 4;
    const int m0 = blockIdx.x * BM, n0 = blockIdx.y * BN;

    f32x4 acc[MR][NR] = {};

    // staging (r8 layout): slot ch=rp*8+s <- (row=2rp|(d&1), kslot=d>>1), d=s^(rp&7)
    auto stageA = [&](int buf, int k0) {
#pragma unroll
        for (int i = 0; i < 2; ++i) {
            int ch = i * THREADS + tid;
            int rp = ch >> 3, s = ch & 7, d = s ^ (rp & 7);
            const u16* g = A + (long)(m0 + ((rp << 1) | (d & 1))) * lda + k0 + ((d >> 1) << 3);
            gload16(g, (char*)As + (size_t)buf * (BM * BK * 2) + ch * 16);
        }
    };
    auto stageB = [&](int buf, int k0) {
#pragma unroll
        for (int i = 0; i < 2; ++i) {
            int ch = i * THREADS + tid;
            int rp = ch >> 3, s = ch & 7, d = s ^ (rp & 7);
            const u16* g = B + (long)(n0 + ((rp << 1) | (d & 1))) * ldb + k0 + ((d >> 1) << 3);
            gload16(g, (char*)Bs + (size_t)buf * (BN * BK * 2) + ch * 16);
        }
    };
    auto lds_off = [&](int row) -> int {
        int rp = row >> 1;
        int s  = ((lk << 1) | (row & 1)) ^ (rp & 7);
        return rp * 64 + s * 8;
    };

    const int nt = K >> 5;

    stageA(0, 0); stageB(0, 0);
    if (nt > 1) { stageA(1, BK); stageB(1, BK); }
    if (nt > 1) waitv<4>(); else waitv<0>();
    __builtin_amdgcn_s_barrier();

    for (int k = 0; k < nt; ++k) {
        const int cur = k % 3;
        const int nxt = (k + 2) % 3;
        const u16* Ac = As + (size_t)cur * (BM * BK);
        const u16* Bc = Bs + (size_t)cur * (BN * BK);
        short8 af[MR], bf[NR];

        // ---- phase 0: B frags + A frags 0..3, stage next A, 16 MFMA ----
#pragma unroll
        for (int n = 0; n < NR; ++n)
            bf[n] = *(const short8*)(Bc + lds_off(wc * 64 + n * 16 + lr));
#pragma unroll
        for (int m = 0; m < 4; ++m)
            af[m] = *(const short8*)(Ac + lds_off(wr * 128 + m * 16 + lr));
        if (k + 2 < nt) stageA(nxt, (k + 2) * BK);
        asm volatile("s_waitcnt lgkmcnt(0)" ::: "memory");
        __builtin_amdgcn_s_setprio(1);
#pragma unroll
        for (int m = 0; m < 4; ++m)
#pragma unroll
            for (int n = 0; n < NR; ++n)
                acc[m][n] = __builtin_amdgcn_mfma_f32_16x16x32_bf16(af[m], bf[n], acc[m][n], 0, 0, 0);
        __builtin_amdgcn_s_setprio(0);

        // ---- phase 1: A frags 4..7 (B reused in regs), stage next B ----
#pragma unroll
        for (int m = 4; m < 8; ++m)
            af[m] = *(const short8*)(Ac + lds_off(wr * 128 + m * 16 + lr));
        if (k + 2 < nt) stageB(nxt, (k + 2) * BK);
        asm volatile("s_waitcnt lgkmcnt(0)" ::: "memory");
        __builtin_amdgcn_s_setprio(1);
#pragma unroll
        for (int m = 4; m < 8; ++m)
#pragma unroll
            for (int n = 0; n < NR; ++n)
                acc[m][n] = __builtin_amdgcn_mfma_f32_16x16x32_bf16(af[m], bf[n], acc[m][n], 0, 0, 0);
        __builtin_amdgcn_s_setprio(0);

        // ---- end of step: tile k+1 landed; tile k+2 (4 loads) in flight ----
        if (k + 1 < nt) {
            if (k + 2 < nt) waitv<4>(); else waitv<0>();
            __builtin_amdgcn_s_barrier();
        }
    }

    // epilogue: col = lane&15, row = (lane>>4)*4 + j
#pragma unroll
    for (int m = 0; m < MR; ++m) {
        const int rowb = m0 + wr * 128 + m * 16 + (lane >> 4) * 4;
#pragma unroll
        for (int n = 0; n < NR; ++n) {
            const int col = n0 + wc * 64 + n * 16 + lr;
            const float bv = bias[col];
#pragma unroll
            for (int j = 0; j < 4; ++j) {
                float v = acc[m][n][j];
                if (EPI == 2) {
                    float t = v + bv;
                    ((u16*)C)[(long)(rowb + j) * ldc + col] =
                        f2bf(0.5f * t * (1.0f + erff(t * 0.70710678118654752f)));
                } else {  // EPI 5: QKV routing
                    const long qidx = (long)(col >> 10) * 4194304L
                                    + (long)(rowb + j) * 1024 + (col & 1023);
                    ((u16*)C)[qidx] = f2bf(v + bv);
                }
            }
        }
    }
}

// ---------------------------------------------------------------------------
// gemm_bt (r7/r10-proven): NBUF=3, counted vmcnt, two barriers per step.
// Used for FFN2/Wo (N=1024 shapes) and attention GEMMs.
// ---------------------------------------------------------------------------
template<int WM, int WN, int MR, int NR, int EPI>
__global__ __launch_bounds__(WM * WN * 64)
void gemm_bt(const u16* __restrict__ A, const u16* __restrict__ B, void* __restrict__ C,
             const float* __restrict__ bias, const float* __restrict__ resid,
             int K, int lda, int ldb, int ldc,
             int nh, long a_zb, long a_zh, long b_zb, long b_zh, long c_zb, long c_zh,
             float scale)
{
    static_assert(WM * WN == 4 || WM * WN == 8, "4 or 8 waves");
    constexpr int THREADS = WM * WN * 64;
    constexpr int BM = WM * MR * 16;
    constexpr int BN = WN * NR * 16;
    constexpr int BK = 32;
    constexpr int NBUF = 3;
    __shared__ __align__(16) u16 As[NBUF * BM * BK];
    __shared__ __align__(16) u16 Bs[NBUF * BN * BK];

    const int tid  = threadIdx.x;
    const int lane = tid & 63;
    const int wid  = tid >> 6;
    const int zz = blockIdx.z;
    const int b = zz / nh, h = zz % nh;
    A += (long)b * a_zb + (long)h * a_zh;
    B += (long)b * b_zb + (long)h * b_zh;
    const long coff = (long)b * c_zb + (long)h * c_zh;
    const int m0 = blockIdx.x * BM, n0 = blockIdx.y * BN;

    f32x4 acc[MR][NR] = {};
    constexpr int AI = (BM * 4) / THREADS;
    constexpr int BI = (BN * 4) / THREADS;
    constexpr int L  = AI + BI;

    const int wr = wid / WN, wc = wid % WN;
    const int lr = lane & 15, lk = lane >> 4;

    auto stage = [&](int buf, int k0) {
#pragma unroll
        for (int i = 0; i < AI; ++i) {
            int ch = i * THREADS + tid;
            int rp = ch >> 3, s = ch & 7;
            int d  = s ^ (rp & 7);
            const u16* g = A + (long)(m0 + ((rp << 1) | (d & 1))) * lda + k0 + ((d >> 1) << 3);
            gload16(g, (char*)As + (size_t)buf * (BM * BK * 2) + ch * 16);
        }
#pragma unroll
        for (int i = 0; i < BI; ++i) {
            int ch = i * THREADS + tid;
            int rp = ch >> 3, s = ch & 7;
            int d  = s ^ (rp & 7);
            const u16* g = B + (long)(n0 + ((rp << 1) | (d & 1))) * ldb + k0 + ((d >> 1) << 3);
            gload16(g, (char*)Bs + (size_t)buf * (BN * BK * 2) + ch * 16);
        }
    };

    auto lds_off = [&](int row) -> int {
        int rp = row >> 1;
        int s  = ((lk << 1) | (row & 1)) ^ (rp & 7);
        return rp * 64 + s * 8;
    };

    const int nt = K >> 5;

    if (nt > 0) stage(0, 0);
    if (nt > 1) stage(1, BK);
    if (nt > 2) stage(2, 2 * BK);
    if (nt > 2)      waitv<2 * L>();
    else if (nt > 1) waitv<L>();
    else             waitv<0>();
    __builtin_amdgcn_s_barrier();

    for (int k = 0; k < nt; ++k) {
        const int cur = k % 3;
        const u16* Ac = As + (size_t)cur * (BM * BK);
        const u16* Bc = Bs + (size_t)cur * (BN * BK);
        short8 af[MR], bf[NR];
#pragma unroll
        for (int m = 0; m < MR; ++m)
            af[m] = *(const short8*)(Ac + lds_off(wr * MR * 16 + m * 16 + lr));
#pragma unroll
        for (int n = 0; n < NR; ++n)
            bf[n] = *(const short8*)(Bc + lds_off(wc * NR * 16 + n * 16 + lr));

        asm volatile("s_waitcnt lgkmcnt(0)" ::: "memory");
        __builtin_amdgcn_s_barrier();

        if (k + 3 < nt) stage(cur, (k + 3) * BK);

#pragma unroll
        for (int m = 0; m < MR; ++m)
#pragma unroll
            for (int n = 0; n < NR; ++n)
                acc[m][n] = __builtin_amdgcn_mfma_f32_16x16x32_bf16(af[m], bf[n], acc[m][n], 0, 0, 0);

        if (k + 1 < nt) {
            if (k + 4 <= nt)      waitv<2 * L>();
            else if (k + 3 == nt) waitv<L>();
            else                  waitv<0>();
            __builtin_amdgcn_s_barrier();
        }
    }

#pragma unroll
    for (int m = 0; m < MR; ++m) {
        const int rowb = m0 + wr * MR * 16 + m * 16 + (lane >> 4) * 4;
#pragma unroll
        for (int n = 0; n < NR; ++n) {
            const int col = n0 + wc * NR * 16 + n * 16 + lr;
            float bv = 0.f;
            if (EPI == 0 || EPI == 1 || EPI == 2 || EPI == 5) bv = bias[col];
#pragma unroll
            for (int j = 0; j < 4; ++j) {
                const long idx = coff + (long)(rowb + j) * ldc + col;
                float v = acc[m][n][j];
                if (EPI == 0) {
                    ((u16*)C)[idx] = f2bf(v + bv);
                } else if (EPI == 1) {
                    ((float*)C)[idx] = v + bv + resid[(long)(rowb + j) * ldc + col];
                } else if (EPI == 2) {
                    float t = v + bv;
                    ((u16*)C)[idx] = f2bf(0.5f * t * (1.0f + erff(t * 0.70710678118654752f)));
                } else if (EPI == 3) {
                    ((u16*)C)[idx] = f2bf(v * scale);
                } else if (EPI == 5) {
                    const long qidx = (long)(col >> 10) * 4194304L
                                    + (long)(rowb + j) * 1024 + (col & 1023);
                    ((u16*)C)[qidx] = f2bf(v + bv);
                } else {
                    ((u16*)C)[idx] = f2bf(v);
                }
            }
        }
    }
}

// ---------------------------------------------------------------------------
__global__ __launch_bounds__(256)
void wconv_kernel(const float* __restrict__ src, u16* __restrict__ dst,
                  int K, int N, int row_off)
{
    __shared__ __align__(16) float t[64][65];
    const float* s = src + (long)(blockIdx.y * 64) * N + blockIdx.x * 64;
    const int tid = threadIdx.x;
#pragma unroll
    for (int i = 0; i < 4; ++i) {
        int ch = (i << 8) + tid;
        int r = ch >> 4, c4 = ch & 15;
        float4 v = *(const float4*)(s + (long)r * N + c4 * 4);
        t[r][c4 * 4 + 0] = v.x; t[r][c4 * 4 + 1] = v.y;
        t[r][c4 * 4 + 2] = v.z; t[r][c4 * 4 + 3] = v.w;
    }
    __syncthreads();
    u16* d = dst + (long)(row_off + blockIdx.x * 64) * K + blockIdx.y * 64;
#pragma unroll
    for (int i = 0; i < 4; ++i) {
        int ch = (i << 8) + tid;
        int c = ch >> 4, k4 = ch & 15;
        ushort4 o;
        o.x = f2bf(t[k4 * 4 + 0][c]);
        o.y = f2bf(t[k4 * 4 + 1][c]);
        o.z = f2bf(t[k4 * 4 + 2][c]);
        o.w = f2bf(t[k4 * 4 + 3][c]);
        *(ushort4*)(d + (long)c * K + k4 * 4) = o;
    }
}

__global__ __launch_bounds__(256)
void bconcat_kernel(const float* __restrict__ bq, const float* __restrict__ bk,
                    const float* __restrict__ bv, float* __restrict__ out)
{
    int i = blockIdx.x * 256 + threadIdx.x;
    int l = i / 3072, n = i % 3072;
    float v = (n < 1024) ? bq[l * 1024 + n]
            : (n < 2048) ? bk[l * 1024 + n - 1024]
                         : bv[l * 1024 + n - 2048];
    out[i] = v;
}

__global__ __launch_bounds__(256)
void embed_kernel(const int* __restrict__ seq, const int* __restrict__ seg,
                  const float* __restrict__ tok, const float* __restrict__ sege,
                  float* __restrict__ x, u16* __restrict__ xb)
{
    long i = ((long)blockIdx.x << 8) + threadIdx.x;
    int d2 = (int)(i & 511);
    long bl = i >> 9;
    int l = (int)(bl & 511);
    int t = seq[bl];
    int g = seg[bl];
    float div = powf(10000.f, -(float)(2 * d2) * (1.0f / 1024.f));
    float arg = (float)l * div;
    float sv = sinf(arg), cv = cosf(arg);
    long toff = (long)t * 1024 + 2 * d2;
    long goff = (long)g * 1024 + 2 * d2;
    float x0 = tok[toff]     + sv + sege[goff];
    float x1 = tok[toff + 1] + cv + sege[goff + 1];
    long xo = (bl << 10) + 2 * d2;
    x[xo] = x0; x[xo + 1] = x1;
    xb[xo] = f2bf(x0); xb[xo + 1] = f2bf(x1);
}

__global__ __launch_bounds__(256)
void vtrans_kernel(const u16* __restrict__ Vb, u16* __restrict__ vt)
{
    __shared__ __align__(16) u16 t[64][72];
    const int bh = blockIdx.y;
    const int l0 = blockIdx.x << 6;
    const u16* src = Vb + ((long)bh << 15) + (long)l0 * 64;
    const int tid = threadIdx.x;
#pragma unroll
    for (int i = 0; i < 2; ++i) {
        int ch = (i << 8) + tid;
        int r = ch >> 3, c8 = ch & 7;
        short8 v = *(const short8*)(src + (long)r * 64 + (c8 << 3));
#pragma unroll
        for (int j = 0; j < 8; ++j) t[r][(c8 << 3) + j] = (u16)v[j];
    }
    __syncthreads();
    u16* d = vt + ((long)bh << 15) + l0;
#pragma unroll
    for (int i = 0; i < 2; ++i) {
        int ch = (i << 8) + tid;
        int dd = ch >> 3, l8 = ch & 7;
        short8 o;
#pragma unroll
        for (int j = 0; j < 8; ++j) o[j] = (short)t[(l8 << 3) + j][dd];
        *(short8*)(d + (long)dd * 512 + (l8 << 3)) = o;
    }
}

__global__ __launch_bounds__(256)
void softmax_kernel(u16* __restrict__ S, const int* __restrict__ seq)
{
    long row = ((long)blockIdx.x << 2) + (threadIdx.x >> 6);
    int lane = threadIdx.x & 63;
    int b = (int)(row >> 13);
    u16* p = S + (row << 9);
    short8 raw = *(short8*)(p + (lane << 3));
    const int* sq = seq + (b << 9) + (lane << 3);
    float v[8];
#pragma unroll
    for (int i = 0; i < 8; ++i)
        v[i] = (sq[i] == 0) ? -1e9f : bf2f((u16)raw[i]);
    float mx = v[0];
#pragma unroll
    for (int i = 1; i < 8; ++i) mx = fmaxf(mx, v[i]);
#pragma unroll
    for (int o = 32; o; o >>= 1) mx = fmaxf(mx, __shfl_xor(mx, o));
    float e[8], sum = 0.f;
#pragma unroll
    for (int i = 0; i < 8; ++i) { e[i] = expf(v[i] - mx); sum += e[i]; }
#pragma unroll
    for (int o = 32; o; o >>= 1) sum += __shfl_xor(sum, o);
    float r = 1.0f / sum;
    short8 o8;
#pragma unroll
    for (int i = 0; i < 8; ++i) o8[i] = (short)f2bf(e[i] * r);
    *(short8*)(p + (lane << 3)) = o8;
}

__global__ __launch_bounds__(256)
void ln_kernel(const float* __restrict__ in, float* __restrict__ xout, u16* __restrict__ xbout)
{
    const int row = blockIdx.x;
    const int tid = threadIdx.x;
    const float4 v = ((const float4*)(in + (long)row * 1024))[tid];
    float s = v.x + v.y + v.z + v.w;
#pragma unroll
    for (int o = 32; o; o >>= 1) s += __shfl_down(s, o);
    __shared__ float red[8];
    const int wid = tid >> 6, lane = tid & 63;
    if (lane == 0) red[wid] = s;
    __syncthreads();
    const float mean = (red[0] + red[1] + red[2] + red[3]) * (1.0f / 1024.f);
    const float dx = v.x - mean, dy = v.y - mean, dz = v.z - mean, dw = v.w - mean;
    float q = dx * dx + dy * dy + dz * dz + dw * dw;
#pragma unroll
    for (int o = 32; o; o >>= 1) q += __shfl_down(q, o);
    if (lane == 0) red[4 + wid] = q;
    __syncthreads();
    const float var = (red[4] + red[5] + red[6] + red[7]) * (1.0f / 1024.f);
    const float inv = rsqrtf(var + 1e-5f);
    float4 o4;
    o4.x = dx * inv; o4.y = dy * inv; o4.z = dz * inv; o4.w = dw * inv;
    ((float4*)(xout + (long)row * 1024))[tid] = o4;
    ushort4 ob;
    ob.x = f2bf(o4.x); ob.y = f2bf(o4.y); ob.z = f2bf(o4.z); ob.w = f2bf(o4.w);
    ((ushort4*)(xbout + (long)row * 1024))[tid] = ob;
}

// ---------------------------------------------------------------------------
extern "C" void kernel_launch(void* const* d_in, const int* in_sizes, int n_in,
                              void* d_out, int out_size, void* d_ws, size_t ws_size,
                              hipStream_t stream)
{
    const int*   seqp = (const int*)d_in[0];
    const int*   segp = (const int*)d_in[1];
    const float* tok  = (const float*)d_in[2];
    const float* sege = (const float*)d_in[3];
    const float* Wq = (const float*)d_in[4];  const float* bq = (const float*)d_in[5];
    const float* Wk = (const float*)d_in[6];  const float* bk = (const float*)d_in[7];
    const float* Wv = (const float*)d_in[8];  const float* bv = (const float*)d_in[9];
    const float* Wo = (const float*)d_in[10]; const float* bo = (const float*)d_in[11];
    const float* W1 = (const float*)d_in[12]; const float* b1 = (const float*)d_in[13];
    const float* W2 = (const float*)d_in[14]; const float* b2 = (const float*)d_in[15];

    char* w = (char*)d_ws;
    auto take = [&](size_t bytes) -> void* {
        void* p = (void*)w; w += (bytes + 255) & ~(size_t)255; return p;
    };
    float* x    = (float*)take(4096UL * 1024 * 4);
    u16*   xb   = (u16*)  take(4096UL * 1024 * 2);
    float* tmp  = (float*)take(4096UL * 1024 * 4);
    u16*   R1   = (u16*)  take(128UL * 512 * 512 * 2);
    u16*   qkv3 = (u16*)  take(3UL * 4096 * 1024 * 2);
    u16*   ctx  = (u16*)  take(4096UL * 1024 * 2);
    u16*   vt   = (u16*)  take(128UL * 64 * 512 * 2);
    u16*   qkvw = (u16*)  take(3072UL * 1024 * 2);
    u16*   wo_t = (u16*)  take(1024UL * 1024 * 2);
    u16*   w1_t = (u16*)  take(4096UL * 1024 * 2);
    u16*   w2_t = (u16*)  take(1024UL * 4096 * 2);
    float* bqkv = (float*)take(6UL * 3072 * 4);

    u16* S    = R1;
    u16* hbuf = R1;
    u16* Vb   = qkv3 + 8388608L;
    u16* Qb   = qkv3;
    u16* Kb   = qkv3 + 4194304L;

    bconcat_kernel<<<72, 256, 0, stream>>>(bq, bk, bv, bqkv);
    embed_kernel<<<8192, 256, 0, stream>>>(seqp, segp, tok, sege, x, xb);

    for (int l = 0; l < 6; ++l) {
        wconv_kernel<<<dim3(16, 16), 256, 0, stream>>>(Wq + (long)l * 1048576L, qkvw, 1024, 1024, 0);
        wconv_kernel<<<dim3(16, 16), 256, 0, stream>>>(Wk + (long)l * 1048576L, qkvw, 1024, 1024, 1024);
        wconv_kernel<<<dim3(16, 16), 256, 0, stream>>>(Wv + (long)l * 1048576L, qkvw, 1024, 1024, 2048);
        wconv_kernel<<<dim3(16, 16), 256, 0, stream>>>(Wo + (long)l * 1048576L, wo_t, 1024, 1024, 0);
        wconv_kernel<<<dim3(64, 16), 256, 0, stream>>>(W1 + (long)l * 4194304L, w1_t, 1024, 4096, 0);
        wconv_kernel<<<dim3(16, 64), 256, 0, stream>>>(W2 + (long)l * 4194304L, w2_t, 4096, 1024, 0);

        // fused QKV: [4096,1024] x [3072,1024]^T, 256^2 tile (192 blocks)
        gemm256<5><<<dim3(16, 12), 512, 0, stream>>>(
            xb, qkvw, qkv3, bqkv + l * 3072, 1024, 1024, 1024, 1024);

        vtrans_kernel<<<dim3(8, 128), 256, 0, stream>>>(Vb, vt);

        // scores per (b,h): Q2[512,64] @ K2[512,64]^T * 0.125
        gemm_bt<2, 2, 4, 4, 3><<<dim3(4, 4, 128), 256, 0, stream>>>(
            Qb, Kb, S, nullptr, nullptr,
            64, 64, 64, 512,
            16, 524288L, 32768L, 524288L, 32768L, 4194304L, 262144L, 0.125f);

        softmax_kernel<<<16384, 256, 0, stream>>>(S, seqp);

        // context per (b,h): P[512,512] @ Vt[64,512]^T -> ctx chunk [512,64]
        gemm_bt<4, 1, 2, 4, 4><<<dim3(4, 1, 128), 256, 0, stream>>>(
            S, vt, ctx, nullptr, nullptr,
            512, 512, 512, 64,
            16, 4194304L, 262144L, 524288L, 32768L, 524288L, 32768L, 1.f);

        // output projection + bias + residual -> tmp fp32 (8-wave 128^2)
        gemm_bt<2, 4, 4, 2, 1><<<dim3(32, 8, 1), 512, 0, stream>>>(
            ctx, wo_t, tmp, bo + l * 1024, x,
            1024, 1024, 1024, 1024, 1, 0, 0, 0, 0, 0, 0, 1.f);

        ln_kernel<<<4096, 256, 0, stream>>>(tmp, x, xb);

        // FFN1 + exact GELU: 256^2 tile (256 blocks)
        gemm256<2><<<dim3(16, 16), 512, 0, stream>>>(
            xb, w1_t, hbuf, b1 + l * 4096, 1024, 1024, 1024, 4096);

        // FFN2 + bias + residual -> tmp fp32 (8-wave 128^2)
        gemm_bt<2, 4, 4, 2, 1><<<dim3(32, 8, 1), 512, 0, stream>>>(
            hbuf, w2_t, tmp, b2 + l * 1024, x,
            4096, 4096, 4096, 1024, 1, 0, 0, 0, 0, 0, 0, 1.f);

        ln_kernel<<<4096, 256, 0, stream>>>(tmp, (l == 5) ? (float*)d_out : x, xb);
    }
}

// Round 12
// 1743.555 us; speedup vs baseline: 1.1695x; 1.0204x over previous
//
#include <hip/hip_runtime.h>
#include <cstdint>
#include <cstddef>

typedef unsigned short u16;
typedef __attribute__((ext_vector_type(8))) short short8;
typedef __attribute__((ext_vector_type(4))) float f32x4;

#define DEV __device__ __forceinline__

DEV float bf2f(u16 u) {
    union { float f; uint32_t i; } c; c.i = ((uint32_t)u) << 16; return c.f;
}
DEV u16 f2bf(float f) {
    union { float f; uint32_t i; } c; c.f = f;
    uint32_t r = c.i + 0x7FFF + ((c.i >> 16) & 1);
    return (u16)(r >> 16);
}

DEV void gload16(const void* g, void* l) {
    __builtin_amdgcn_global_load_lds(
        (const __attribute__((address_space(1))) void*)g,
        (__attribute__((address_space(3))) void*)l, 16, 0, 0);
}

template<int N> DEV void waitv() {
    if constexpr (N == 0)      asm volatile("s_waitcnt vmcnt(0)" ::: "memory");
    else if constexpr (N == 2) asm volatile("s_waitcnt vmcnt(2)" ::: "memory");
    else if constexpr (N == 3) asm volatile("s_waitcnt vmcnt(3)" ::: "memory");
    else if constexpr (N == 4) asm volatile("s_waitcnt vmcnt(4)" ::: "memory");
    else if constexpr (N == 6) asm volatile("s_waitcnt vmcnt(6)" ::: "memory");
    else if constexpr (N == 8) asm volatile("s_waitcnt vmcnt(8)" ::: "memory");
    else                       asm volatile("s_waitcnt vmcnt(0)" ::: "memory");
}

// ---------------------------------------------------------------------------
// Fused attention: per (64-q-tile, head) block: QK^T -> masked softmax -> PV.
// Bit-identical to the previous 3-kernel path: same MFMA accumulation order
// (k ascending), same bf16 rounding points (S bf16*0.125 before softmax, P
// bf16 before PV), same per-row softmax lane mapping and shuffle order.
// S/P live in one 64KB LDS buffer with slot-XOR(q&7) on 16B slots so both
// the row-contiguous softmax access and the PV A-frag access are bank-spread.
// Q/K/V fragments are read directly from global (L2-hot small chunks).
// ---------------------------------------------------------------------------
__global__ __launch_bounds__(512)
void attn_kernel(const u16* __restrict__ Qb, const u16* __restrict__ Kb,
                 const u16* __restrict__ vt, const int* __restrict__ seq,
                 u16* __restrict__ ctx)
{
    __shared__ __align__(16) u16 Ss[64 * 512];   // 64KB, S then P in place
    const int tid = threadIdx.x, lane = tid & 63, wid = tid >> 6;
    const int bh = blockIdx.y;          // b*16+h
    const int b  = bh >> 4;
    const int q0 = blockIdx.x << 6;     // 64-row q tile
    const u16* Qh = Qb + ((long)bh << 15) + (long)q0 * 64;  // [64,64] contig
    const u16* Kh = Kb + ((long)bh << 15);                  // [512,64] contig
    const u16* Vh = vt + ((long)bh << 15);                  // [64,512] d-major
    const int lr = lane & 15, lk = lane >> 4;

    // ---- scores: wave wid owns k-cols [wid*64, +64), all 64 q rows ----
    f32x4 sacc[4][4] = {};
    {
        short8 af[4], bf[4];
#pragma unroll
        for (int s = 0; s < 2; ++s) {           // K-contraction 64 = 2 steps
#pragma unroll
            for (int m = 0; m < 4; ++m)
                af[m] = *(const short8*)(Qh + (long)(m * 16 + lr) * 64 + s * 32 + lk * 8);
#pragma unroll
            for (int n = 0; n < 4; ++n)
                bf[n] = *(const short8*)(Kh + (long)(wid * 64 + n * 16 + lr) * 64 + s * 32 + lk * 8);
#pragma unroll
            for (int m = 0; m < 4; ++m)
#pragma unroll
                for (int n = 0; n < 4; ++n)
                    sacc[m][n] = __builtin_amdgcn_mfma_f32_16x16x32_bf16(af[m], bf[n], sacc[m][n], 0, 0, 0);
        }
    }
    // write S bf16 (*0.125) with slot-XOR(q&7) on 16B slots
#pragma unroll
    for (int m = 0; m < 4; ++m) {
#pragma unroll
        for (int n = 0; n < 4; ++n) {
            const int k = wid * 64 + n * 16 + lr;
#pragma unroll
            for (int j = 0; j < 4; ++j) {
                const int q = m * 16 + (lane >> 4) * 4 + j;
                const int col = (((k >> 3) ^ (q & 7)) << 3) | (k & 7);
                Ss[q * 512 + col] = f2bf(sacc[m][n][j] * 0.125f);
            }
        }
    }
    __syncthreads();

    // ---- masked softmax: wave wid handles rows wid*8 .. wid*8+7 ----
    const int* sq = seq + (b << 9) + (lane << 3);
    int msk[8];
#pragma unroll
    for (int i = 0; i < 8; ++i) msk[i] = sq[i];
#pragma unroll
    for (int r = 0; r < 8; ++r) {
        const int q = wid * 8 + r;
        u16* p = Ss + q * 512 + ((lane ^ (q & 7)) << 3);   // lane's 8-k slot
        short8 raw = *(short8*)p;
        float v[8];
#pragma unroll
        for (int i = 0; i < 8; ++i)
            v[i] = (msk[i] == 0) ? -1e9f : bf2f((u16)raw[i]);
        float mx = v[0];
#pragma unroll
        for (int i = 1; i < 8; ++i) mx = fmaxf(mx, v[i]);
#pragma unroll
        for (int o = 32; o; o >>= 1) mx = fmaxf(mx, __shfl_xor(mx, o));
        float e[8], sum = 0.f;
#pragma unroll
        for (int i = 0; i < 8; ++i) { e[i] = expf(v[i] - mx); sum += e[i]; }
#pragma unroll
        for (int o = 32; o; o >>= 1) sum += __shfl_xor(sum, o);
        float rr = 1.0f / sum;
        short8 o8;
#pragma unroll
        for (int i = 0; i < 8; ++i) o8[i] = (short)f2bf(e[i] * rr);
        *(short8*)p = o8;
    }
    __syncthreads();

    // ---- PV: out 64q x 64d; wave (wr=wid>>1: q16-tile, wc2=wid&1: d32) ----
    const int wr = wid >> 1, wc2 = wid & 1;
    f32x4 pacc[2] = {};
#pragma unroll
    for (int ks = 0; ks < 16; ++ks) {          // K=512 ascending, step 32
        const int qrow = wr * 16 + lr;
        short8 pa = *(const short8*)(Ss + qrow * 512 + (((ks * 4 + lk) ^ (qrow & 7)) << 3));
        short8 vb[2];
#pragma unroll
        for (int n = 0; n < 2; ++n) {
            const int d = wc2 * 32 + n * 16 + lr;
            vb[n] = *(const short8*)(Vh + (long)d * 512 + ks * 32 + lk * 8);
        }
#pragma unroll
        for (int n = 0; n < 2; ++n)
            pacc[n] = __builtin_amdgcn_mfma_f32_16x16x32_bf16(pa, vb[n], pacc[n], 0, 0, 0);
    }
    u16* Ch = ctx + ((long)bh << 15) + (long)q0 * 64;
#pragma unroll
    for (int n = 0; n < 2; ++n) {
        const int d = wc2 * 32 + n * 16 + lr;
#pragma unroll
        for (int j = 0; j < 4; ++j) {
            const int q = wr * 16 + (lane >> 4) * 4 + j;
            Ch[(long)q * 64 + d] = f2bf(pacc[n][j]);
        }
    }
}

// ---------------------------------------------------------------------------
// gemm256: 256x256 tile, BK=32, 8 waves, NBUF=3, 2 MFMA sub-phases/step.
// ---------------------------------------------------------------------------
template<int EPI>
__global__ __launch_bounds__(512)
void gemm256(const u16* __restrict__ A, const u16* __restrict__ B, void* __restrict__ C,
             const float* __restrict__ bias,
             int K, int lda, int ldb, int ldc)
{
    constexpr int THREADS = 512;
    constexpr int BM = 256, BN = 256, BK = 32;
    constexpr int MR = 8, NR = 4;
    __shared__ __align__(16) u16 As[3 * BM * BK];
    __shared__ __align__(16) u16 Bs[3 * BN * BK];

    const int tid = threadIdx.x, lane = tid & 63, wid = tid >> 6;
    const int wr = wid >> 2, wc = wid & 3;
    const int lr = lane & 15, lk = lane >> 4;
    const int m0 = blockIdx.x * BM, n0 = blockIdx.y * BN;

    f32x4 acc[MR][NR] = {};

    auto stageA = [&](int buf, int k0) {
#pragma unroll
        for (int i = 0; i < 2; ++i) {
            int ch = i * THREADS + tid;
            int rp = ch >> 3, s = ch & 7, d = s ^ (rp & 7);
            const u16* g = A + (long)(m0 + ((rp << 1) | (d & 1))) * lda + k0 + ((d >> 1) << 3);
            gload16(g, (char*)As + (size_t)buf * (BM * BK * 2) + ch * 16);
        }
    };
    auto stageB = [&](int buf, int k0) {
#pragma unroll
        for (int i = 0; i < 2; ++i) {
            int ch = i * THREADS + tid;
            int rp = ch >> 3, s = ch & 7, d = s ^ (rp & 7);
            const u16* g = B + (long)(n0 + ((rp << 1) | (d & 1))) * ldb + k0 + ((d >> 1) << 3);
            gload16(g, (char*)Bs + (size_t)buf * (BN * BK * 2) + ch * 16);
        }
    };
    auto lds_off = [&](int row) -> int {
        int rp = row >> 1;
        int s  = ((lk << 1) | (row & 1)) ^ (rp & 7);
        return rp * 64 + s * 8;
    };

    const int nt = K >> 5;

    stageA(0, 0); stageB(0, 0);
    if (nt > 1) { stageA(1, BK); stageB(1, BK); }
    if (nt > 1) waitv<4>(); else waitv<0>();
    __builtin_amdgcn_s_barrier();

    for (int k = 0; k < nt; ++k) {
        const int cur = k % 3;
        const int nxt = (k + 2) % 3;
        const u16* Ac = As + (size_t)cur * (BM * BK);
        const u16* Bc = Bs + (size_t)cur * (BN * BK);
        short8 af[MR], bf[NR];

#pragma unroll
        for (int n = 0; n < NR; ++n)
            bf[n] = *(const short8*)(Bc + lds_off(wc * 64 + n * 16 + lr));
#pragma unroll
        for (int m = 0; m < 4; ++m)
            af[m] = *(const short8*)(Ac + lds_off(wr * 128 + m * 16 + lr));
        if (k + 2 < nt) stageA(nxt, (k + 2) * BK);
        asm volatile("s_waitcnt lgkmcnt(0)" ::: "memory");
        __builtin_amdgcn_s_setprio(1);
#pragma unroll
        for (int m = 0; m < 4; ++m)
#pragma unroll
            for (int n = 0; n < NR; ++n)
                acc[m][n] = __builtin_amdgcn_mfma_f32_16x16x32_bf16(af[m], bf[n], acc[m][n], 0, 0, 0);
        __builtin_amdgcn_s_setprio(0);

#pragma unroll
        for (int m = 4; m < 8; ++m)
            af[m] = *(const short8*)(Ac + lds_off(wr * 128 + m * 16 + lr));
        if (k + 2 < nt) stageB(nxt, (k + 2) * BK);
        asm volatile("s_waitcnt lgkmcnt(0)" ::: "memory");
        __builtin_amdgcn_s_setprio(1);
#pragma unroll
        for (int m = 4; m < 8; ++m)
#pragma unroll
            for (int n = 0; n < NR; ++n)
                acc[m][n] = __builtin_amdgcn_mfma_f32_16x16x32_bf16(af[m], bf[n], acc[m][n], 0, 0, 0);
        __builtin_amdgcn_s_setprio(0);

        if (k + 1 < nt) {
            if (k + 2 < nt) waitv<4>(); else waitv<0>();
            __builtin_amdgcn_s_barrier();
        }
    }

#pragma unroll
    for (int m = 0; m < MR; ++m) {
        const int rowb = m0 + wr * 128 + m * 16 + (lane >> 4) * 4;
#pragma unroll
        for (int n = 0; n < NR; ++n) {
            const int col = n0 + wc * 64 + n * 16 + lr;
            const float bv = bias[col];
#pragma unroll
            for (int j = 0; j < 4; ++j) {
                float v = acc[m][n][j];
                if (EPI == 2) {
                    float t = v + bv;
                    ((u16*)C)[(long)(rowb + j) * ldc + col] =
                        f2bf(0.5f * t * (1.0f + erff(t * 0.70710678118654752f)));
                } else {  // EPI 5: QKV routing
                    const long qidx = (long)(col >> 10) * 4194304L
                                    + (long)(rowb + j) * 1024 + (col & 1023);
                    ((u16*)C)[qidx] = f2bf(v + bv);
                }
            }
        }
    }
}

// ---------------------------------------------------------------------------
// gemm_bt (r7-proven): NBUF=3, counted vmcnt, two barriers per step.
// ---------------------------------------------------------------------------
template<int WM, int WN, int MR, int NR, int EPI>
__global__ __launch_bounds__(WM * WN * 64)
void gemm_bt(const u16* __restrict__ A, const u16* __restrict__ B, void* __restrict__ C,
             const float* __restrict__ bias, const float* __restrict__ resid,
             int K, int lda, int ldb, int ldc,
             int nh, long a_zb, long a_zh, long b_zb, long b_zh, long c_zb, long c_zh,
             float scale)
{
    static_assert(WM * WN == 4 || WM * WN == 8, "4 or 8 waves");
    constexpr int THREADS = WM * WN * 64;
    constexpr int BM = WM * MR * 16;
    constexpr int BN = WN * NR * 16;
    constexpr int BK = 32;
    constexpr int NBUF = 3;
    __shared__ __align__(16) u16 As[NBUF * BM * BK];
    __shared__ __align__(16) u16 Bs[NBUF * BN * BK];

    const int tid  = threadIdx.x;
    const int lane = tid & 63;
    const int wid  = tid >> 6;
    const int zz = blockIdx.z;
    const int b = zz / nh, h = zz % nh;
    A += (long)b * a_zb + (long)h * a_zh;
    B += (long)b * b_zb + (long)h * b_zh;
    const long coff = (long)b * c_zb + (long)h * c_zh;
    const int m0 = blockIdx.x * BM, n0 = blockIdx.y * BN;

    f32x4 acc[MR][NR] = {};
    constexpr int AI = (BM * 4) / THREADS;
    constexpr int BI = (BN * 4) / THREADS;
    constexpr int L  = AI + BI;

    const int wr = wid / WN, wc = wid % WN;
    const int lr = lane & 15, lk = lane >> 4;

    auto stage = [&](int buf, int k0) {
#pragma unroll
        for (int i = 0; i < AI; ++i) {
            int ch = i * THREADS + tid;
            int rp = ch >> 3, s = ch & 7;
            int d  = s ^ (rp & 7);
            const u16* g = A + (long)(m0 + ((rp << 1) | (d & 1))) * lda + k0 + ((d >> 1) << 3);
            gload16(g, (char*)As + (size_t)buf * (BM * BK * 2) + ch * 16);
        }
#pragma unroll
        for (int i = 0; i < BI; ++i) {
            int ch = i * THREADS + tid;
            int rp = ch >> 3, s = ch & 7;
            int d  = s ^ (rp & 7);
            const u16* g = B + (long)(n0 + ((rp << 1) | (d & 1))) * ldb + k0 + ((d >> 1) << 3);
            gload16(g, (char*)Bs + (size_t)buf * (BN * BK * 2) + ch * 16);
        }
    };

    auto lds_off = [&](int row) -> int {
        int rp = row >> 1;
        int s  = ((lk << 1) | (row & 1)) ^ (rp & 7);
        return rp * 64 + s * 8;
    };

    const int nt = K >> 5;

    if (nt > 0) stage(0, 0);
    if (nt > 1) stage(1, BK);
    if (nt > 2) stage(2, 2 * BK);
    if (nt > 2)      waitv<2 * L>();
    else if (nt > 1) waitv<L>();
    else             waitv<0>();
    __builtin_amdgcn_s_barrier();

    for (int k = 0; k < nt; ++k) {
        const int cur = k % 3;
        const u16* Ac = As + (size_t)cur * (BM * BK);
        const u16* Bc = Bs + (size_t)cur * (BN * BK);
        short8 af[MR], bf[NR];
#pragma unroll
        for (int m = 0; m < MR; ++m)
            af[m] = *(const short8*)(Ac + lds_off(wr * MR * 16 + m * 16 + lr));
#pragma unroll
        for (int n = 0; n < NR; ++n)
            bf[n] = *(const short8*)(Bc + lds_off(wc * NR * 16 + n * 16 + lr));

        asm volatile("s_waitcnt lgkmcnt(0)" ::: "memory");
        __builtin_amdgcn_s_barrier();

        if (k + 3 < nt) stage(cur, (k + 3) * BK);

#pragma unroll
        for (int m = 0; m < MR; ++m)
#pragma unroll
            for (int n = 0; n < NR; ++n)
                acc[m][n] = __builtin_amdgcn_mfma_f32_16x16x32_bf16(af[m], bf[n], acc[m][n], 0, 0, 0);

        if (k + 1 < nt) {
            if (k + 4 <= nt)      waitv<2 * L>();
            else if (k + 3 == nt) waitv<L>();
            else                  waitv<0>();
            __builtin_amdgcn_s_barrier();
        }
    }

#pragma unroll
    for (int m = 0; m < MR; ++m) {
        const int rowb = m0 + wr * MR * 16 + m * 16 + (lane >> 4) * 4;
#pragma unroll
        for (int n = 0; n < NR; ++n) {
            const int col = n0 + wc * NR * 16 + n * 16 + lr;
            float bv = 0.f;
            if (EPI == 0 || EPI == 1 || EPI == 2 || EPI == 5) bv = bias[col];
#pragma unroll
            for (int j = 0; j < 4; ++j) {
                const long idx = coff + (long)(rowb + j) * ldc + col;
                float v = acc[m][n][j];
                if (EPI == 0) {
                    ((u16*)C)[idx] = f2bf(v + bv);
                } else if (EPI == 1) {
                    ((float*)C)[idx] = v + bv + resid[(long)(rowb + j) * ldc + col];
                } else if (EPI == 2) {
                    float t = v + bv;
                    ((u16*)C)[idx] = f2bf(0.5f * t * (1.0f + erff(t * 0.70710678118654752f)));
                } else if (EPI == 3) {
                    ((u16*)C)[idx] = f2bf(v * scale);
                } else if (EPI == 5) {
                    const long qidx = (long)(col >> 10) * 4194304L
                                    + (long)(rowb + j) * 1024 + (col & 1023);
                    ((u16*)C)[qidx] = f2bf(v + bv);
                } else {
                    ((u16*)C)[idx] = f2bf(v);
                }
            }
        }
    }
}

// ---------------------------------------------------------------------------
__global__ __launch_bounds__(256)
void wconv_kernel(const float* __restrict__ src, u16* __restrict__ dst,
                  int K, int N, int row_off)
{
    __shared__ __align__(16) float t[64][65];
    const float* s = src + (long)(blockIdx.y * 64) * N + blockIdx.x * 64;
    const int tid = threadIdx.x;
#pragma unroll
    for (int i = 0; i < 4; ++i) {
        int ch = (i << 8) + tid;
        int r = ch >> 4, c4 = ch & 15;
        float4 v = *(const float4*)(s + (long)r * N + c4 * 4);
        t[r][c4 * 4 + 0] = v.x; t[r][c4 * 4 + 1] = v.y;
        t[r][c4 * 4 + 2] = v.z; t[r][c4 * 4 + 3] = v.w;
    }
    __syncthreads();
    u16* d = dst + (long)(row_off + blockIdx.x * 64) * K + blockIdx.y * 64;
#pragma unroll
    for (int i = 0; i < 4; ++i) {
        int ch = (i << 8) + tid;
        int c = ch >> 4, k4 = ch & 15;
        ushort4 o;
        o.x = f2bf(t[k4 * 4 + 0][c]);
        o.y = f2bf(t[k4 * 4 + 1][c]);
        o.z = f2bf(t[k4 * 4 + 2][c]);
        o.w = f2bf(t[k4 * 4 + 3][c]);
        *(ushort4*)(d + (long)c * K + k4 * 4) = o;
    }
}

__global__ __launch_bounds__(256)
void bconcat_kernel(const float* __restrict__ bq, const float* __restrict__ bk,
                    const float* __restrict__ bv, float* __restrict__ out)
{
    int i = blockIdx.x * 256 + threadIdx.x;
    int l = i / 3072, n = i % 3072;
    float v = (n < 1024) ? bq[l * 1024 + n]
            : (n < 2048) ? bk[l * 1024 + n - 1024]
                         : bv[l * 1024 + n - 2048];
    out[i] = v;
}

__global__ __launch_bounds__(256)
void embed_kernel(const int* __restrict__ seq, const int* __restrict__ seg,
                  const float* __restrict__ tok, const float* __restrict__ sege,
                  float* __restrict__ x, u16* __restrict__ xb)
{
    long i = ((long)blockIdx.x << 8) + threadIdx.x;
    int d2 = (int)(i & 511);
    long bl = i >> 9;
    int l = (int)(bl & 511);
    int t = seq[bl];
    int g = seg[bl];
    float div = powf(10000.f, -(float)(2 * d2) * (1.0f / 1024.f));
    float arg = (float)l * div;
    float sv = sinf(arg), cv = cosf(arg);
    long toff = (long)t * 1024 + 2 * d2;
    long goff = (long)g * 1024 + 2 * d2;
    float x0 = tok[toff]     + sv + sege[goff];
    float x1 = tok[toff + 1] + cv + sege[goff + 1];
    long xo = (bl << 10) + 2 * d2;
    x[xo] = x0; x[xo + 1] = x1;
    xb[xo] = f2bf(x0); xb[xo + 1] = f2bf(x1);
}

__global__ __launch_bounds__(256)
void vtrans_kernel(const u16* __restrict__ Vb, u16* __restrict__ vt)
{
    __shared__ __align__(16) u16 t[64][72];
    const int bh = blockIdx.y;
    const int l0 = blockIdx.x << 6;
    const u16* src = Vb + ((long)bh << 15) + (long)l0 * 64;
    const int tid = threadIdx.x;
#pragma unroll
    for (int i = 0; i < 2; ++i) {
        int ch = (i << 8) + tid;
        int r = ch >> 3, c8 = ch & 7;
        short8 v = *(const short8*)(src + (long)r * 64 + (c8 << 3));
#pragma unroll
        for (int j = 0; j < 8; ++j) t[r][(c8 << 3) + j] = (u16)v[j];
    }
    __syncthreads();
    u16* d = vt + ((long)bh << 15) + l0;
#pragma unroll
    for (int i = 0; i < 2; ++i) {
        int ch = (i << 8) + tid;
        int dd = ch >> 3, l8 = ch & 7;
        short8 o;
#pragma unroll
        for (int j = 0; j < 8; ++j) o[j] = (short)t[(l8 << 3) + j][dd];
        *(short8*)(d + (long)dd * 512 + (l8 << 3)) = o;
    }
}

__global__ __launch_bounds__(256)
void ln_kernel(const float* __restrict__ in, float* __restrict__ xout, u16* __restrict__ xbout)
{
    const int row = blockIdx.x;
    const int tid = threadIdx.x;
    const float4 v = ((const float4*)(in + (long)row * 1024))[tid];
    float s = v.x + v.y + v.z + v.w;
#pragma unroll
    for (int o = 32; o; o >>= 1) s += __shfl_down(s, o);
    __shared__ float red[8];
    const int wid = tid >> 6, lane = tid & 63;
    if (lane == 0) red[wid] = s;
    __syncthreads();
    const float mean = (red[0] + red[1] + red[2] + red[3]) * (1.0f / 1024.f);
    const float dx = v.x - mean, dy = v.y - mean, dz = v.z - mean, dw = v.w - mean;
    float q = dx * dx + dy * dy + dz * dz + dw * dw;
#pragma unroll
    for (int o = 32; o; o >>= 1) q += __shfl_down(q, o);
    if (lane == 0) red[4 + wid] = q;
    __syncthreads();
    const float var = (red[4] + red[5] + red[6] + red[7]) * (1.0f / 1024.f);
    const float inv = rsqrtf(var + 1e-5f);
    float4 o4;
    o4.x = dx * inv; o4.y = dy * inv; o4.z = dz * inv; o4.w = dw * inv;
    ((float4*)(xout + (long)row * 1024))[tid] = o4;
    ushort4 ob;
    ob.x = f2bf(o4.x); ob.y = f2bf(o4.y); ob.z = f2bf(o4.z); ob.w = f2bf(o4.w);
    ((ushort4*)(xbout + (long)row * 1024))[tid] = ob;
}

// ---------------------------------------------------------------------------
extern "C" void kernel_launch(void* const* d_in, const int* in_sizes, int n_in,
                              void* d_out, int out_size, void* d_ws, size_t ws_size,
                              hipStream_t stream)
{
    const int*   seqp = (const int*)d_in[0];
    const int*   segp = (const int*)d_in[1];
    const float* tok  = (const float*)d_in[2];
    const float* sege = (const float*)d_in[3];
    const float* Wq = (const float*)d_in[4];  const float* bq = (const float*)d_in[5];
    const float* Wk = (const float*)d_in[6];  const float* bk = (const float*)d_in[7];
    const float* Wv = (const float*)d_in[8];  const float* bv = (const float*)d_in[9];
    const float* Wo = (const float*)d_in[10]; const float* bo = (const float*)d_in[11];
    const float* W1 = (const float*)d_in[12]; const float* b1 = (const float*)d_in[13];
    const float* W2 = (const float*)d_in[14]; const float* b2 = (const float*)d_in[15];

    char* w = (char*)d_ws;
    auto take = [&](size_t bytes) -> void* {
        void* p = (void*)w; w += (bytes + 255) & ~(size_t)255; return p;
    };
    float* x    = (float*)take(4096UL * 1024 * 4);
    u16*   xb   = (u16*)  take(4096UL * 1024 * 2);
    float* tmp  = (float*)take(4096UL * 1024 * 4);
    u16*   R1   = (u16*)  take(128UL * 512 * 512 * 2);
    u16*   qkv3 = (u16*)  take(3UL * 4096 * 1024 * 2);
    u16*   ctx  = (u16*)  take(4096UL * 1024 * 2);
    u16*   vt   = (u16*)  take(128UL * 64 * 512 * 2);
    u16*   qkvw = (u16*)  take(3072UL * 1024 * 2);
    u16*   wo_t = (u16*)  take(1024UL * 1024 * 2);
    u16*   w1_t = (u16*)  take(4096UL * 1024 * 2);
    u16*   w2_t = (u16*)  take(1024UL * 4096 * 2);
    float* bqkv = (float*)take(6UL * 3072 * 4);

    u16* hbuf = R1;              // FFN hidden (S no longer materialized)
    u16* Qb   = qkv3;
    u16* Kb   = qkv3 + 4194304L;
    u16* Vb   = qkv3 + 8388608L;

    bconcat_kernel<<<72, 256, 0, stream>>>(bq, bk, bv, bqkv);
    embed_kernel<<<8192, 256, 0, stream>>>(seqp, segp, tok, sege, x, xb);

    for (int l = 0; l < 6; ++l) {
        wconv_kernel<<<dim3(16, 16), 256, 0, stream>>>(Wq + (long)l * 1048576L, qkvw, 1024, 1024, 0);
        wconv_kernel<<<dim3(16, 16), 256, 0, stream>>>(Wk + (long)l * 1048576L, qkvw, 1024, 1024, 1024);
        wconv_kernel<<<dim3(16, 16), 256, 0, stream>>>(Wv + (long)l * 1048576L, qkvw, 1024, 1024, 2048);
        wconv_kernel<<<dim3(16, 16), 256, 0, stream>>>(Wo + (long)l * 1048576L, wo_t, 1024, 1024, 0);
        wconv_kernel<<<dim3(64, 16), 256, 0, stream>>>(W1 + (long)l * 4194304L, w1_t, 1024, 4096, 0);
        wconv_kernel<<<dim3(16, 64), 256, 0, stream>>>(W2 + (long)l * 4194304L, w2_t, 4096, 1024, 0);

        // fused QKV: 256^2 tile (192 blocks); routes col>>10 to Qb/Kb/Vb
        gemm256<5><<<dim3(16, 12), 512, 0, stream>>>(
            xb, qkvw, qkv3, bqkv + l * 3072, 1024, 1024, 1024, 1024);

        // per-head V transpose: [512,64] -> [64,512]
        vtrans_kernel<<<dim3(8, 128), 256, 0, stream>>>(Vb, vt);

        // fused attention: QK^T -> masked softmax -> PV  (replaces 3 kernels)
        attn_kernel<<<dim3(8, 128), 512, 0, stream>>>(Qb, Kb, vt, seqp, ctx);

        // output projection + bias + residual -> tmp fp32 (8-wave 128^2)
        gemm_bt<2, 4, 4, 2, 1><<<dim3(32, 8, 1), 512, 0, stream>>>(
            ctx, wo_t, tmp, bo + l * 1024, x,
            1024, 1024, 1024, 1024, 1, 0, 0, 0, 0, 0, 0, 1.f);

        ln_kernel<<<4096, 256, 0, stream>>>(tmp, x, xb);

        // FFN1 + exact GELU: 256^2 tile (256 blocks)
        gemm256<2><<<dim3(16, 16), 512, 0, stream>>>(
            xb, w1_t, hbuf, b1 + l * 4096, 1024, 1024, 1024, 4096);

        // FFN2 + bias + residual -> tmp fp32 (8-wave 128^2)
        gemm_bt<2, 4, 4, 2, 1><<<dim3(32, 8, 1), 512, 0, stream>>>(
            hbuf, w2_t, tmp, b2 + l * 1024, x,
            4096, 4096, 4096, 1024, 1, 0, 0, 0, 0, 0, 0, 1.f);

        ln_kernel<<<4096, 256, 0, stream>>>(tmp, (l == 5) ? (float*)d_out : x, xb);
    }
}

// Round 13
// 1662.585 us; speedup vs baseline: 1.2264x; 1.0487x over previous
//
#include <hip/hip_runtime.h>
#include <cstdint>
#include <cstddef>

typedef unsigned short u16;
typedef __attribute__((ext_vector_type(8))) short short8;
typedef __attribute__((ext_vector_type(4))) float f32x4;

#define DEV __device__ __forceinline__

DEV float bf2f(u16 u) {
    union { float f; uint32_t i; } c; c.i = ((uint32_t)u) << 16; return c.f;
}
DEV u16 f2bf(float f) {
    union { float f; uint32_t i; } c; c.f = f;
    uint32_t r = c.i + 0x7FFF + ((c.i >> 16) & 1);
    return (u16)(r >> 16);
}

DEV void gload16(const void* g, void* l) {
    __builtin_amdgcn_global_load_lds(
        (const __attribute__((address_space(1))) void*)g,
        (__attribute__((address_space(3))) void*)l, 16, 0, 0);
}

template<int N> DEV void waitv() {
    if constexpr (N == 0)      asm volatile("s_waitcnt vmcnt(0)" ::: "memory");
    else if constexpr (N == 2) asm volatile("s_waitcnt vmcnt(2)" ::: "memory");
    else if constexpr (N == 3) asm volatile("s_waitcnt vmcnt(3)" ::: "memory");
    else if constexpr (N == 4) asm volatile("s_waitcnt vmcnt(4)" ::: "memory");
    else if constexpr (N == 6) asm volatile("s_waitcnt vmcnt(6)" ::: "memory");
    else if constexpr (N == 8) asm volatile("s_waitcnt vmcnt(8)" ::: "memory");
    else                       asm volatile("s_waitcnt vmcnt(0)" ::: "memory");
}

// ---------------------------------------------------------------------------
// gemm_k64: FFN2 kernel. A and B in BLOCKED K-major layout [K/64][rows][64]
// so each staging wave reads 1KB fully contiguous (attacks the measured
// ~950 GB/s scattered-64B HBM ceiling). BK=64, 128x128 tile, 8 waves, NBUF=3,
// r7-proven loop {reads; lgkm0; BAR; stage(k+3); MFMA(2 sub-steps, k asc);
// vmcnt(counted); BAR}. MFMA accumulation order identical to BK=32 version.
// EPI: f32 out = acc + bias[col] + resid[row*1024+col].
// ---------------------------------------------------------------------------
__global__ __launch_bounds__(512)
void gemm_k64(const u16* __restrict__ Ablk, const u16* __restrict__ Bblk,
              float* __restrict__ C, const float* __restrict__ bias,
              const float* __restrict__ resid, int K, int Mtot, int Ntot)
{
    constexpr int THREADS = 512;
    constexpr int BM = 128, BN = 128, BK = 64;
    constexpr int MR = 4, NR = 2;          // 8 waves: 2M x 4N, 64x32/wave
    __shared__ __align__(16) u16 As[3 * BM * BK];
    __shared__ __align__(16) u16 Bs[3 * BN * BK];

    const int tid = threadIdx.x, lane = tid & 63, wid = tid >> 6;
    const int wr = wid >> 2, wc = wid & 3;
    const int lr = lane & 15, lk = lane >> 4;
    const int m0 = blockIdx.x * BM, n0 = blockIdx.y * BN;
    const long planeA = (long)Mtot * 64, planeB = (long)Ntot * 64;

    f32x4 acc[MR][NR] = {};

    // stage one 128row x 64k tile: chunk ch -> row=ch>>3, s=ch&7, d=s^(row&7)
    // global (blocked): plane(k0>>6) + (r0+row)*64 + d*8  -> per-row 128B
    // contiguous, 8 rows per wave => 1KB contiguous per wave-instruction.
    auto stageA = [&](int buf, int k0) {
#pragma unroll
        for (int i = 0; i < 2; ++i) {
            int ch = i * THREADS + tid;
            int row = ch >> 3, s = ch & 7, d = s ^ (row & 7);
            const u16* g = Ablk + (long)(k0 >> 6) * planeA + (long)(m0 + row) * 64 + d * 8;
            gload16(g, (char*)As + (size_t)buf * (BM * BK * 2) + ch * 16);
        }
    };
    auto stageB = [&](int buf, int k0) {
#pragma unroll
        for (int i = 0; i < 2; ++i) {
            int ch = i * THREADS + tid;
            int row = ch >> 3, s = ch & 7, d = s ^ (row & 7);
            const u16* g = Bblk + (long)(k0 >> 6) * planeB + (long)(n0 + row) * 64 + d * 8;
            gload16(g, (char*)Bs + (size_t)buf * (BN * BK * 2) + ch * 16);
        }
    };
    // read (row, k-slot ks=khalf*4+lk): u16 offset = row*64 + (ks^(row&7))*8
    auto lds_off = [&](int row, int ks) -> int {
        return row * 64 + ((ks ^ (row & 7)) << 3);
    };

    const int nt = K >> 6;   // 64 steps for K=4096

    stageA(0, 0); stageB(0, 0);
    if (nt > 1) { stageA(1, 64); stageB(1, 64); }
    if (nt > 2) { stageA(2, 128); stageB(2, 128); }
    if (nt > 2)      waitv<8>();
    else if (nt > 1) waitv<4>();
    else             waitv<0>();
    __builtin_amdgcn_s_barrier();

    for (int k = 0; k < nt; ++k) {
        const int cur = k % 3;
        const u16* Ac = As + (size_t)cur * (BM * BK);
        const u16* Bc = Bs + (size_t)cur * (BN * BK);
        short8 af[2][MR], bf[2][NR];
#pragma unroll
        for (int h = 0; h < 2; ++h) {
#pragma unroll
            for (int m = 0; m < MR; ++m)
                af[h][m] = *(const short8*)(Ac + lds_off(wr * 64 + m * 16 + lr, h * 4 + lk));
#pragma unroll
            for (int n = 0; n < NR; ++n)
                bf[h][n] = *(const short8*)(Bc + lds_off(wc * 32 + n * 16 + lr, h * 4 + lk));
        }

        asm volatile("s_waitcnt lgkmcnt(0)" ::: "memory");
        __builtin_amdgcn_s_barrier();

        if (k + 3 < nt) { stageA(cur, (k + 3) * 64); stageB(cur, (k + 3) * 64); }

        __builtin_amdgcn_s_setprio(1);
#pragma unroll
        for (int h = 0; h < 2; ++h)          // k ascending: lo 32 then hi 32
#pragma unroll
            for (int m = 0; m < MR; ++m)
#pragma unroll
                for (int n = 0; n < NR; ++n)
                    acc[m][n] = __builtin_amdgcn_mfma_f32_16x16x32_bf16(af[h][m], bf[h][n], acc[m][n], 0, 0, 0);
        __builtin_amdgcn_s_setprio(0);

        if (k + 1 < nt) {
            if (k + 4 <= nt)      waitv<8>();
            else if (k + 3 == nt) waitv<4>();
            else                  waitv<0>();
            __builtin_amdgcn_s_barrier();
        }
    }

#pragma unroll
    for (int m = 0; m < MR; ++m) {
        const int rowb = m0 + wr * 64 + m * 16 + (lane >> 4) * 4;
#pragma unroll
        for (int n = 0; n < NR; ++n) {
            const int col = n0 + wc * 32 + n * 16 + lr;
            const float bv = bias[col];
#pragma unroll
            for (int j = 0; j < 4; ++j) {
                const long idx = (long)(rowb + j) * 1024 + col;
                C[idx] = acc[m][n][j] + bv + resid[idx];
            }
        }
    }
}

// ---------------------------------------------------------------------------
// Fused attention (r12-proven): QK^T -> masked softmax -> PV, bit-identical.
// ---------------------------------------------------------------------------
__global__ __launch_bounds__(512)
void attn_kernel(const u16* __restrict__ Qb, const u16* __restrict__ Kb,
                 const u16* __restrict__ vt, const int* __restrict__ seq,
                 u16* __restrict__ ctx)
{
    __shared__ __align__(16) u16 Ss[64 * 512];
    const int tid = threadIdx.x, lane = tid & 63, wid = tid >> 6;
    const int bh = blockIdx.y;
    const int b  = bh >> 4;
    const int q0 = blockIdx.x << 6;
    const u16* Qh = Qb + ((long)bh << 15) + (long)q0 * 64;
    const u16* Kh = Kb + ((long)bh << 15);
    const u16* Vh = vt + ((long)bh << 15);
    const int lr = lane & 15, lk = lane >> 4;

    f32x4 sacc[4][4] = {};
    {
        short8 af[4], bf[4];
#pragma unroll
        for (int s = 0; s < 2; ++s) {
#pragma unroll
            for (int m = 0; m < 4; ++m)
                af[m] = *(const short8*)(Qh + (long)(m * 16 + lr) * 64 + s * 32 + lk * 8);
#pragma unroll
            for (int n = 0; n < 4; ++n)
                bf[n] = *(const short8*)(Kh + (long)(wid * 64 + n * 16 + lr) * 64 + s * 32 + lk * 8);
#pragma unroll
            for (int m = 0; m < 4; ++m)
#pragma unroll
                for (int n = 0; n < 4; ++n)
                    sacc[m][n] = __builtin_amdgcn_mfma_f32_16x16x32_bf16(af[m], bf[n], sacc[m][n], 0, 0, 0);
        }
    }
#pragma unroll
    for (int m = 0; m < 4; ++m) {
#pragma unroll
        for (int n = 0; n < 4; ++n) {
            const int k = wid * 64 + n * 16 + lr;
#pragma unroll
            for (int j = 0; j < 4; ++j) {
                const int q = m * 16 + (lane >> 4) * 4 + j;
                const int col = (((k >> 3) ^ (q & 7)) << 3) | (k & 7);
                Ss[q * 512 + col] = f2bf(sacc[m][n][j] * 0.125f);
            }
        }
    }
    __syncthreads();

    const int* sq = seq + (b << 9) + (lane << 3);
    int msk[8];
#pragma unroll
    for (int i = 0; i < 8; ++i) msk[i] = sq[i];
#pragma unroll
    for (int r = 0; r < 8; ++r) {
        const int q = wid * 8 + r;
        u16* p = Ss + q * 512 + ((lane ^ (q & 7)) << 3);
        short8 raw = *(short8*)p;
        float v[8];
#pragma unroll
        for (int i = 0; i < 8; ++i)
            v[i] = (msk[i] == 0) ? -1e9f : bf2f((u16)raw[i]);
        float mx = v[0];
#pragma unroll
        for (int i = 1; i < 8; ++i) mx = fmaxf(mx, v[i]);
#pragma unroll
        for (int o = 32; o; o >>= 1) mx = fmaxf(mx, __shfl_xor(mx, o));
        float e[8], sum = 0.f;
#pragma unroll
        for (int i = 0; i < 8; ++i) { e[i] = expf(v[i] - mx); sum += e[i]; }
#pragma unroll
        for (int o = 32; o; o >>= 1) sum += __shfl_xor(sum, o);
        float rr = 1.0f / sum;
        short8 o8;
#pragma unroll
        for (int i = 0; i < 8; ++i) o8[i] = (short)f2bf(e[i] * rr);
        *(short8*)p = o8;
    }
    __syncthreads();

    const int wr = wid >> 1, wc2 = wid & 1;
    f32x4 pacc[2] = {};
#pragma unroll
    for (int ks = 0; ks < 16; ++ks) {
        const int qrow = wr * 16 + lr;
        short8 pa = *(const short8*)(Ss + qrow * 512 + (((ks * 4 + lk) ^ (qrow & 7)) << 3));
        short8 vb[2];
#pragma unroll
        for (int n = 0; n < 2; ++n) {
            const int d = wc2 * 32 + n * 16 + lr;
            vb[n] = *(const short8*)(Vh + (long)d * 512 + ks * 32 + lk * 8);
        }
#pragma unroll
        for (int n = 0; n < 2; ++n)
            pacc[n] = __builtin_amdgcn_mfma_f32_16x16x32_bf16(pa, vb[n], pacc[n], 0, 0, 0);
    }
    u16* Ch = ctx + ((long)bh << 15) + (long)q0 * 64;
#pragma unroll
    for (int n = 0; n < 2; ++n) {
        const int d = wc2 * 32 + n * 16 + lr;
#pragma unroll
        for (int j = 0; j < 4; ++j) {
            const int q = wr * 16 + (lane >> 4) * 4 + j;
            Ch[(long)q * 64 + d] = f2bf(pacc[n][j]);
        }
    }
}

// ---------------------------------------------------------------------------
// gemm256 (r11-proven): 256x256 tile, BK=32, 8 waves, NBUF=3.
// EPI 5: bf16 = acc+bias routed by col>>10 (QKV).
// EPI 6: bf16 = gelu(acc+bias) written to BLOCKED hbuf [k/64][4096][64].
// ---------------------------------------------------------------------------
template<int EPI>
__global__ __launch_bounds__(512)
void gemm256(const u16* __restrict__ A, const u16* __restrict__ B, void* __restrict__ C,
             const float* __restrict__ bias,
             int K, int lda, int ldb, int ldc)
{
    constexpr int THREADS = 512;
    constexpr int BM = 256, BN = 256, BK = 32;
    constexpr int MR = 8, NR = 4;
    __shared__ __align__(16) u16 As[3 * BM * BK];
    __shared__ __align__(16) u16 Bs[3 * BN * BK];

    const int tid = threadIdx.x, lane = tid & 63, wid = tid >> 6;
    const int wr = wid >> 2, wc = wid & 3;
    const int lr = lane & 15, lk = lane >> 4;
    const int m0 = blockIdx.x * BM, n0 = blockIdx.y * BN;

    f32x4 acc[MR][NR] = {};

    auto stageA = [&](int buf, int k0) {
#pragma unroll
        for (int i = 0; i < 2; ++i) {
            int ch = i * THREADS + tid;
            int rp = ch >> 3, s = ch & 7, d = s ^ (rp & 7);
            const u16* g = A + (long)(m0 + ((rp << 1) | (d & 1))) * lda + k0 + ((d >> 1) << 3);
            gload16(g, (char*)As + (size_t)buf * (BM * BK * 2) + ch * 16);
        }
    };
    auto stageB = [&](int buf, int k0) {
#pragma unroll
        for (int i = 0; i < 2; ++i) {
            int ch = i * THREADS + tid;
            int rp = ch >> 3, s = ch & 7, d = s ^ (rp & 7);
            const u16* g = B + (long)(n0 + ((rp << 1) | (d & 1))) * ldb + k0 + ((d >> 1) << 3);
            gload16(g, (char*)Bs + (size_t)buf * (BN * BK * 2) + ch * 16);
        }
    };
    auto lds_off = [&](int row) -> int {
        int rp = row >> 1;
        int s  = ((lk << 1) | (row & 1)) ^ (rp & 7);
        return rp * 64 + s * 8;
    };

    const int nt = K >> 5;

    stageA(0, 0); stageB(0, 0);
    if (nt > 1) { stageA(1, BK); stageB(1, BK); }
    if (nt > 1) waitv<4>(); else waitv<0>();
    __builtin_amdgcn_s_barrier();

    for (int k = 0; k < nt; ++k) {
        const int cur = k % 3;
        const int nxt = (k + 2) % 3;
        const u16* Ac = As + (size_t)cur * (BM * BK);
        const u16* Bc = Bs + (size_t)cur * (BN * BK);
        short8 af[MR], bf[NR];

#pragma unroll
        for (int n = 0; n < NR; ++n)
            bf[n] = *(const short8*)(Bc + lds_off(wc * 64 + n * 16 + lr));
#pragma unroll
        for (int m = 0; m < 4; ++m)
            af[m] = *(const short8*)(Ac + lds_off(wr * 128 + m * 16 + lr));
        if (k + 2 < nt) stageA(nxt, (k + 2) * BK);
        asm volatile("s_waitcnt lgkmcnt(0)" ::: "memory");
        __builtin_amdgcn_s_setprio(1);
#pragma unroll
        for (int m = 0; m < 4; ++m)
#pragma unroll
            for (int n = 0; n < NR; ++n)
                acc[m][n] = __builtin_amdgcn_mfma_f32_16x16x32_bf16(af[m], bf[n], acc[m][n], 0, 0, 0);
        __builtin_amdgcn_s_setprio(0);

#pragma unroll
        for (int m = 4; m < 8; ++m)
            af[m] = *(const short8*)(Ac + lds_off(wr * 128 + m * 16 + lr));
        if (k + 2 < nt) stageB(nxt, (k + 2) * BK);
        asm volatile("s_waitcnt lgkmcnt(0)" ::: "memory");
        __builtin_amdgcn_s_setprio(1);
#pragma unroll
        for (int m = 4; m < 8; ++m)
#pragma unroll
            for (int n = 0; n < NR; ++n)
                acc[m][n] = __builtin_amdgcn_mfma_f32_16x16x32_bf16(af[m], bf[n], acc[m][n], 0, 0, 0);
        __builtin_amdgcn_s_setprio(0);

        if (k + 1 < nt) {
            if (k + 2 < nt) waitv<4>(); else waitv<0>();
            __builtin_amdgcn_s_barrier();
        }
    }

#pragma unroll
    for (int m = 0; m < MR; ++m) {
        const int rowb = m0 + wr * 128 + m * 16 + (lane >> 4) * 4;
#pragma unroll
        for (int n = 0; n < NR; ++n) {
            const int col = n0 + wc * 64 + n * 16 + lr;
            const float bv = bias[col];
#pragma unroll
            for (int j = 0; j < 4; ++j) {
                float v = acc[m][n][j];
                if (EPI == 6) {
                    // blocked hbuf: [col>>6][row][col&63], plane = 4096*64
                    float t = v + bv;
                    ((u16*)C)[(long)(col >> 6) * 262144L + (long)(rowb + j) * 64 + (col & 63)]
                        = f2bf(0.5f * t * (1.0f + erff(t * 0.70710678118654752f)));
                } else {  // EPI 5: QKV routing
                    const long qidx = (long)(col >> 10) * 4194304L
                                    + (long)(rowb + j) * 1024 + (col & 1023);
                    ((u16*)C)[qidx] = f2bf(v + bv);
                }
            }
        }
    }
}

// ---------------------------------------------------------------------------
// gemm_bt (r7-proven): used for Wo (EPI 1).
// ---------------------------------------------------------------------------
template<int WM, int WN, int MR, int NR, int EPI>
__global__ __launch_bounds__(WM * WN * 64)
void gemm_bt(const u16* __restrict__ A, const u16* __restrict__ B, void* __restrict__ C,
             const float* __restrict__ bias, const float* __restrict__ resid,
             int K, int lda, int ldb, int ldc)
{
    constexpr int THREADS = WM * WN * 64;
    constexpr int BM = WM * MR * 16;
    constexpr int BN = WN * NR * 16;
    constexpr int BK = 32;
    __shared__ __align__(16) u16 As[3 * BM * BK];
    __shared__ __align__(16) u16 Bs[3 * BN * BK];

    const int tid  = threadIdx.x;
    const int lane = tid & 63;
    const int wid  = tid >> 6;
    const int m0 = blockIdx.x * BM, n0 = blockIdx.y * BN;

    f32x4 acc[MR][NR] = {};
    constexpr int AI = (BM * 4) / THREADS;
    constexpr int BI = (BN * 4) / THREADS;
    constexpr int L  = AI + BI;

    const int wr = wid / WN, wc = wid % WN;
    const int lr = lane & 15, lk = lane >> 4;

    auto stage = [&](int buf, int k0) {
#pragma unroll
        for (int i = 0; i < AI; ++i) {
            int ch = i * THREADS + tid;
            int rp = ch >> 3, s = ch & 7;
            int d  = s ^ (rp & 7);
            const u16* g = A + (long)(m0 + ((rp << 1) | (d & 1))) * lda + k0 + ((d >> 1) << 3);
            gload16(g, (char*)As + (size_t)buf * (BM * BK * 2) + ch * 16);
        }
#pragma unroll
        for (int i = 0; i < BI; ++i) {
            int ch = i * THREADS + tid;
            int rp = ch >> 3, s = ch & 7;
            int d  = s ^ (rp & 7);
            const u16* g = B + (long)(n0 + ((rp << 1) | (d & 1))) * ldb + k0 + ((d >> 1) << 3);
            gload16(g, (char*)Bs + (size_t)buf * (BN * BK * 2) + ch * 16);
        }
    };

    auto lds_off = [&](int row) -> int {
        int rp = row >> 1;
        int s  = ((lk << 1) | (row & 1)) ^ (rp & 7);
        return rp * 64 + s * 8;
    };

    const int nt = K >> 5;

    if (nt > 0) stage(0, 0);
    if (nt > 1) stage(1, BK);
    if (nt > 2) stage(2, 2 * BK);
    if (nt > 2)      waitv<2 * L>();
    else if (nt > 1) waitv<L>();
    else             waitv<0>();
    __builtin_amdgcn_s_barrier();

    for (int k = 0; k < nt; ++k) {
        const int cur = k % 3;
        const u16* Ac = As + (size_t)cur * (BM * BK);
        const u16* Bc = Bs + (size_t)cur * (BN * BK);
        short8 af[MR], bf[NR];
#pragma unroll
        for (int m = 0; m < MR; ++m)
            af[m] = *(const short8*)(Ac + lds_off(wr * MR * 16 + m * 16 + lr));
#pragma unroll
        for (int n = 0; n < NR; ++n)
            bf[n] = *(const short8*)(Bc + lds_off(wc * NR * 16 + n * 16 + lr));

        asm volatile("s_waitcnt lgkmcnt(0)" ::: "memory");
        __builtin_amdgcn_s_barrier();

        if (k + 3 < nt) stage(cur, (k + 3) * BK);

#pragma unroll
        for (int m = 0; m < MR; ++m)
#pragma unroll
            for (int n = 0; n < NR; ++n)
                acc[m][n] = __builtin_amdgcn_mfma_f32_16x16x32_bf16(af[m], bf[n], acc[m][n], 0, 0, 0);

        if (k + 1 < nt) {
            if (k + 4 <= nt)      waitv<2 * L>();
            else if (k + 3 == nt) waitv<L>();
            else                  waitv<0>();
            __builtin_amdgcn_s_barrier();
        }
    }

#pragma unroll
    for (int m = 0; m < MR; ++m) {
        const int rowb = m0 + wr * MR * 16 + m * 16 + (lane >> 4) * 4;
#pragma unroll
        for (int n = 0; n < NR; ++n) {
            const int col = n0 + wc * NR * 16 + n * 16 + lr;
            const float bv = bias[col];
#pragma unroll
            for (int j = 0; j < 4; ++j) {
                const long idx = (long)(rowb + j) * ldc + col;
                ((float*)C)[idx] = acc[m][n][j] + bv + resid[idx];
            }
        }
    }
}

// ---------------------------------------------------------------------------
// wconv (z-batched): src fp32 [Z][K][N] tile -> dst bf16 [Z][row_off+N][K]
// ---------------------------------------------------------------------------
__global__ __launch_bounds__(256)
void wconv_kernel(const float* __restrict__ src, u16* __restrict__ dst,
                  int K, int N, int row_off, long src_z, long dst_z)
{
    __shared__ __align__(16) float t[64][65];
    const int z = blockIdx.z;
    const float* s = src + (long)z * src_z + (long)(blockIdx.y * 64) * N + blockIdx.x * 64;
    const int tid = threadIdx.x;
#pragma unroll
    for (int i = 0; i < 4; ++i) {
        int ch = (i << 8) + tid;
        int r = ch >> 4, c4 = ch & 15;
        float4 v = *(const float4*)(s + (long)r * N + c4 * 4);
        t[r][c4 * 4 + 0] = v.x; t[r][c4 * 4 + 1] = v.y;
        t[r][c4 * 4 + 2] = v.z; t[r][c4 * 4 + 3] = v.w;
    }
    __syncthreads();
    u16* d = dst + (long)z * dst_z + (long)(row_off + blockIdx.x * 64) * K + blockIdx.y * 64;
#pragma unroll
    for (int i = 0; i < 4; ++i) {
        int ch = (i << 8) + tid;
        int c = ch >> 4, k4 = ch & 15;
        ushort4 o;
        o.x = f2bf(t[k4 * 4 + 0][c]);
        o.y = f2bf(t[k4 * 4 + 1][c]);
        o.z = f2bf(t[k4 * 4 + 2][c]);
        o.w = f2bf(t[k4 * 4 + 3][c]);
        *(ushort4*)(d + (long)c * K + k4 * 4) = o;
    }
}

// ---------------------------------------------------------------------------
// wconv_blk: src fp32 [Z][K][N] -> dst bf16 BLOCKED [Z][K/64][N][64]
// ---------------------------------------------------------------------------
__global__ __launch_bounds__(256)
void wconv_blk(const float* __restrict__ src, u16* __restrict__ dst,
               int N, long src_z, long dst_z)
{
    __shared__ __align__(16) float t[64][65];
    const int z = blockIdx.z;
    const int k0 = blockIdx.x * 64, n0 = blockIdx.y * 64;
    const float* s = src + (long)z * src_z + (long)k0 * N + n0;
    const int tid = threadIdx.x;
#pragma unroll
    for (int i = 0; i < 4; ++i) {
        int ch = (i << 8) + tid;
        int r = ch >> 4, c4 = ch & 15;        // r = k within tile, c = n
        float4 v = *(const float4*)(s + (long)r * N + c4 * 4);
        t[r][c4 * 4 + 0] = v.x; t[r][c4 * 4 + 1] = v.y;
        t[r][c4 * 4 + 2] = v.z; t[r][c4 * 4 + 3] = v.w;
    }
    __syncthreads();
    u16* d = dst + (long)z * dst_z + (long)blockIdx.x * N * 64 + (long)n0 * 64;
#pragma unroll
    for (int i = 0; i < 4; ++i) {
        int ch = (i << 8) + tid;
        int c = ch >> 4, k4 = ch & 15;        // c = n within tile, k4*4 = k
        ushort4 o;
        o.x = f2bf(t[k4 * 4 + 0][c]);
        o.y = f2bf(t[k4 * 4 + 1][c]);
        o.z = f2bf(t[k4 * 4 + 2][c]);
        o.w = f2bf(t[k4 * 4 + 3][c]);
        *(ushort4*)(d + (long)c * 64 + k4 * 4) = o;
    }
}

__global__ __launch_bounds__(256)
void bconcat_kernel(const float* __restrict__ bq, const float* __restrict__ bk,
                    const float* __restrict__ bv, float* __restrict__ out)
{
    int i = blockIdx.x * 256 + threadIdx.x;
    int l = i / 3072, n = i % 3072;
    float v = (n < 1024) ? bq[l * 1024 + n]
            : (n < 2048) ? bk[l * 1024 + n - 1024]
                         : bv[l * 1024 + n - 2048];
    out[i] = v;
}

__global__ __launch_bounds__(256)
void embed_kernel(const int* __restrict__ seq, const int* __restrict__ seg,
                  const float* __restrict__ tok, const float* __restrict__ sege,
                  float* __restrict__ x, u16* __restrict__ xb)
{
    long i = ((long)blockIdx.x << 8) + threadIdx.x;
    int d2 = (int)(i & 511);
    long bl = i >> 9;
    int l = (int)(bl & 511);
    int t = seq[bl];
    int g = seg[bl];
    float div = powf(10000.f, -(float)(2 * d2) * (1.0f / 1024.f));
    float arg = (float)l * div;
    float sv = sinf(arg), cv = cosf(arg);
    long toff = (long)t * 1024 + 2 * d2;
    long goff = (long)g * 1024 + 2 * d2;
    float x0 = tok[toff]     + sv + sege[goff];
    float x1 = tok[toff + 1] + cv + sege[goff + 1];
    long xo = (bl << 10) + 2 * d2;
    x[xo] = x0; x[xo + 1] = x1;
    xb[xo] = f2bf(x0); xb[xo + 1] = f2bf(x1);
}

__global__ __launch_bounds__(256)
void vtrans_kernel(const u16* __restrict__ Vb, u16* __restrict__ vt)
{
    __shared__ __align__(16) u16 t[64][72];
    const int bh = blockIdx.y;
    const int l0 = blockIdx.x << 6;
    const u16* src = Vb + ((long)bh << 15) + (long)l0 * 64;
    const int tid = threadIdx.x;
#pragma unroll
    for (int i = 0; i < 2; ++i) {
        int ch = (i << 8) + tid;
        int r = ch >> 3, c8 = ch & 7;
        short8 v = *(const short8*)(src + (long)r * 64 + (c8 << 3));
#pragma unroll
        for (int j = 0; j < 8; ++j) t[r][(c8 << 3) + j] = (u16)v[j];
    }
    __syncthreads();
    u16* d = vt + ((long)bh << 15) + l0;
#pragma unroll
    for (int i = 0; i < 2; ++i) {
        int ch = (i << 8) + tid;
        int dd = ch >> 3, l8 = ch & 7;
        short8 o;
#pragma unroll
        for (int j = 0; j < 8; ++j) o[j] = (short)t[(l8 << 3) + j][dd];
        *(short8*)(d + (long)dd * 512 + (l8 << 3)) = o;
    }
}

__global__ __launch_bounds__(256)
void ln_kernel(const float* __restrict__ in, float* __restrict__ xout, u16* __restrict__ xbout)
{
    const int row = blockIdx.x;
    const int tid = threadIdx.x;
    const float4 v = ((const float4*)(in + (long)row * 1024))[tid];
    float s = v.x + v.y + v.z + v.w;
#pragma unroll
    for (int o = 32; o; o >>= 1) s += __shfl_down(s, o);
    __shared__ float red[8];
    const int wid = tid >> 6, lane = tid & 63;
    if (lane == 0) red[wid] = s;
    __syncthreads();
    const float mean = (red[0] + red[1] + red[2] + red[3]) * (1.0f / 1024.f);
    const float dx = v.x - mean, dy = v.y - mean, dz = v.z - mean, dw = v.w - mean;
    float q = dx * dx + dy * dy + dz * dz + dw * dw;
#pragma unroll
    for (int o = 32; o; o >>= 1) q += __shfl_down(q, o);
    if (lane == 0) red[4 + wid] = q;
    __syncthreads();
    const float var = (red[4] + red[5] + red[6] + red[7]) * (1.0f / 1024.f);
    const float inv = rsqrtf(var + 1e-5f);
    float4 o4;
    o4.x = dx * inv; o4.y = dy * inv; o4.z = dz * inv; o4.w = dw * inv;
    ((float4*)(xout + (long)row * 1024))[tid] = o4;
    ushort4 ob;
    ob.x = f2bf(o4.x); ob.y = f2bf(o4.y); ob.z = f2bf(o4.z); ob.w = f2bf(o4.w);
    ((ushort4*)(xbout + (long)row * 1024))[tid] = ob;
}

// ---------------------------------------------------------------------------
extern "C" void kernel_launch(void* const* d_in, const int* in_sizes, int n_in,
                              void* d_out, int out_size, void* d_ws, size_t ws_size,
                              hipStream_t stream)
{
    const int*   seqp = (const int*)d_in[0];
    const int*   segp = (const int*)d_in[1];
    const float* tok  = (const float*)d_in[2];
    const float* sege = (const float*)d_in[3];
    const float* Wq = (const float*)d_in[4];  const float* bq = (const float*)d_in[5];
    const float* Wk = (const float*)d_in[6];  const float* bk = (const float*)d_in[7];
    const float* Wv = (const float*)d_in[8];  const float* bv = (const float*)d_in[9];
    const float* Wo = (const float*)d_in[10]; const float* bo = (const float*)d_in[11];
    const float* W1 = (const float*)d_in[12]; const float* b1 = (const float*)d_in[13];
    const float* W2 = (const float*)d_in[14]; const float* b2 = (const float*)d_in[15];

    char* w = (char*)d_ws;
    auto take = [&](size_t bytes) -> void* {
        void* p = (void*)w; w += (bytes + 255) & ~(size_t)255; return p;
    };
    float* x    = (float*)take(4096UL * 1024 * 4);      // 16 MB
    u16*   xb   = (u16*)  take(4096UL * 1024 * 2);      //  8 MB
    float* tmp  = (float*)take(4096UL * 1024 * 4);      // 16 MB
    u16*   hbuf = (u16*)  take(4096UL * 4096 * 2);      // 32 MB (blocked)
    u16*   qkv3 = (u16*)  take(3UL * 4096 * 1024 * 2);  // 24 MB
    u16*   ctx  = (u16*)  take(4096UL * 1024 * 2);      //  8 MB
    u16*   vt   = (u16*)  take(128UL * 64 * 512 * 2);   //  8 MB
    u16*   qkvw6= (u16*)  take(6UL * 3072 * 1024 * 2);  // 36 MB
    u16*   wo6  = (u16*)  take(6UL * 1024 * 1024 * 2);  // 12 MB
    u16*   w16  = (u16*)  take(6UL * 4096 * 1024 * 2);  // 48 MB
    u16*   w2b6 = (u16*)  take(6UL * 64 * 1024 * 64 * 2); // 48 MB (blocked)
    float* bqkv = (float*)take(6UL * 3072 * 4);

    u16* Qb = qkv3;
    u16* Kb = qkv3 + 4194304L;
    u16* Vb = qkv3 + 8388608L;

    // ---- one-time prep (6 launches, all layers batched via z) ----
    bconcat_kernel<<<72, 256, 0, stream>>>(bq, bk, bv, bqkv);
    wconv_kernel<<<dim3(16, 16, 6), 256, 0, stream>>>(Wq, qkvw6, 1024, 1024, 0,    1048576L, 3145728L);
    wconv_kernel<<<dim3(16, 16, 6), 256, 0, stream>>>(Wk, qkvw6, 1024, 1024, 1024, 1048576L, 3145728L);
    wconv_kernel<<<dim3(16, 16, 6), 256, 0, stream>>>(Wv, qkvw6, 1024, 1024, 2048, 1048576L, 3145728L);
    wconv_kernel<<<dim3(16, 16, 6), 256, 0, stream>>>(Wo, wo6,   1024, 1024, 0,    1048576L, 1048576L);
    wconv_kernel<<<dim3(64, 16, 6), 256, 0, stream>>>(W1, w16,   1024, 4096, 0,    4194304L, 4194304L);
    wconv_blk  <<<dim3(64, 16, 6), 256, 0, stream>>>(W2, w2b6,  1024,            4194304L, 4194304L);

    embed_kernel<<<8192, 256, 0, stream>>>(seqp, segp, tok, sege, x, xb);

    for (int l = 0; l < 6; ++l) {
        // fused QKV: 256^2 tile; routes col>>10 to Qb/Kb/Vb
        gemm256<5><<<dim3(16, 12), 512, 0, stream>>>(
            xb, qkvw6 + (long)l * 3145728L, qkv3, bqkv + l * 3072, 1024, 1024, 1024, 1024);

        vtrans_kernel<<<dim3(8, 128), 256, 0, stream>>>(Vb, vt);

        attn_kernel<<<dim3(8, 128), 512, 0, stream>>>(Qb, Kb, vt, seqp, ctx);

        // output projection + bias + residual -> tmp fp32
        gemm_bt<2, 4, 4, 2, 1><<<dim3(32, 8), 512, 0, stream>>>(
            ctx, wo6 + (long)l * 1048576L, tmp, bo + l * 1024, x,
            1024, 1024, 1024, 1024);

        ln_kernel<<<4096, 256, 0, stream>>>(tmp, x, xb);

        // FFN1 + GELU -> BLOCKED hbuf [k/64][4096][64]
        gemm256<6><<<dim3(16, 16), 512, 0, stream>>>(
            xb, w16 + (long)l * 4194304L, hbuf, b1 + l * 4096, 1024, 1024, 1024, 4096);

        // FFN2 (blocked A+B, BK=64, coalesced staging) + bias + resid -> tmp
        gemm_k64<<<dim3(32, 8), 512, 0, stream>>>(
            hbuf, w2b6 + (long)l * 4194304L, tmp, b2 + l * 1024, x,
            4096, 4096, 1024);

        ln_kernel<<<4096, 256, 0, stream>>>(tmp, (l == 5) ? (float*)d_out : x, xb);
    }
}